// Round 1
// baseline (727.489 us; speedup 1.0000x reference)
//
#include <hip/hip_runtime.h>

#define N_NODES 50000
#define N_EDGES 800000
#define E_TOT   (N_EDGES + N_NODES)   // with self loops: 850000
#define IN_F    129
#define HID     32
#define HEADS   4
#define F1      (HEADS * HID)     // 128
#define NCLS    40
#define F2      (HEADS * NCLS)    // 160
#define NEG     0.2f
#define BN_EPS  1e-5f

// ---------------- BatchNorm (eval) ----------------
__global__ __launch_bounds__(256) void bn_kernel(
    const float* __restrict__ x, const float* __restrict__ g,
    const float* __restrict__ b, const float* __restrict__ mu,
    const float* __restrict__ var, float* __restrict__ out) {
  int i = blockIdx.x * 256 + threadIdx.x;
  if (i >= N_NODES * IN_F) return;
  int c = i % IN_F;
  out[i] = (x[i] - mu[c]) * rsqrtf(var[c] + BN_EPS) * g[c] + b[c];
}

// ---------------- GEMM1: [N,129] x [129,128] ----------------
// wave handles 8 nodes; lane covers f=lane and f=lane+64
__global__ __launch_bounds__(256) void gemm1_kernel(
    const float* __restrict__ h0, const float* __restrict__ W,
    float* __restrict__ h1) {
  int lane = threadIdx.x & 63;
  int wave = (blockIdx.x * blockDim.x + threadIdx.x) >> 6;
  int nbase = wave * 8;
  if (nbase >= N_NODES) return;
  const float* rows[8];
#pragma unroll
  for (int i = 0; i < 8; i++) {
    int n = nbase + i; if (n > N_NODES - 1) n = N_NODES - 1;
    rows[i] = h0 + (size_t)n * IN_F;
  }
  float a0[8] = {}, a1[8] = {};
  for (int k = 0; k < IN_F; k++) {
    float w0 = W[k * F1 + lane];
    float w1 = W[k * F1 + 64 + lane];
#pragma unroll
    for (int i = 0; i < 8; i++) {
      float xk = rows[i][k];
      a0[i] += xk * w0;
      a1[i] += xk * w1;
    }
  }
#pragma unroll
  for (int i = 0; i < 8; i++) {
    int n = nbase + i;
    if (n >= N_NODES) break;
    h1[(size_t)n * F1 + lane]      = a0[i];
    h1[(size_t)n * F1 + 64 + lane] = a1[i];
  }
}

// ---------------- GEMM2: [N,128] x [128,160] ----------------
__global__ __launch_bounds__(256) void gemm2_kernel(
    const float* __restrict__ hin, const float* __restrict__ W,
    float* __restrict__ hout) {
  int lane = threadIdx.x & 63;
  int wave = (blockIdx.x * blockDim.x + threadIdx.x) >> 6;
  int nbase = wave * 8;
  if (nbase >= N_NODES) return;
  const float* rows[8];
#pragma unroll
  for (int i = 0; i < 8; i++) {
    int n = nbase + i; if (n > N_NODES - 1) n = N_NODES - 1;
    rows[i] = hin + (size_t)n * F1;
  }
  float a0[8] = {}, a1[8] = {}, a2[8] = {};
  bool third = lane < 32;
  for (int k = 0; k < F1; k++) {
    float w0 = W[k * F2 + lane];
    float w1 = W[k * F2 + 64 + lane];
    float w2 = third ? W[k * F2 + 128 + lane] : 0.f;
#pragma unroll
    for (int i = 0; i < 8; i++) {
      float xk = rows[i][k];
      a0[i] += xk * w0;
      a1[i] += xk * w1;
      a2[i] += xk * w2;
    }
  }
#pragma unroll
  for (int i = 0; i < 8; i++) {
    int n = nbase + i;
    if (n >= N_NODES) break;
    hout[(size_t)n * F2 + lane]      = a0[i];
    hout[(size_t)n * F2 + 64 + lane] = a1[i];
    if (third) hout[(size_t)n * F2 + 128 + lane] = a2[i];
  }
}

// ---------------- attention scalars ----------------
// thread per (node, head): dot over channels
__global__ __launch_bounds__(256) void alpha1_kernel(
    const float* __restrict__ h1, const float* __restrict__ a_src,
    const float* __restrict__ a_dst, float* __restrict__ as,
    float* __restrict__ ad) {
  int t = blockIdx.x * 256 + threadIdx.x;
  if (t >= N_NODES * HEADS) return;
  int n = t >> 2, h = t & 3;
  const float* hp = h1 + (size_t)n * F1 + h * HID;
  const float* sp = a_src + h * HID;
  const float* dp = a_dst + h * HID;
  float s = 0.f, d = 0.f;
#pragma unroll
  for (int c = 0; c < HID; c++) { float v = hp[c]; s += v * sp[c]; d += v * dp[c]; }
  as[t] = s; ad[t] = d;
}

__global__ __launch_bounds__(256) void alpha2_kernel(
    const float* __restrict__ h2, const float* __restrict__ a_src,
    const float* __restrict__ a_dst, float* __restrict__ as,
    float* __restrict__ ad) {
  int t = blockIdx.x * 256 + threadIdx.x;
  if (t >= N_NODES * HEADS) return;
  int n = t >> 2, h = t & 3;
  const float* hp = h2 + (size_t)n * F2 + h * NCLS;
  const float* sp = a_src + h * NCLS;
  const float* dp = a_dst + h * NCLS;
  float s = 0.f, d = 0.f;
#pragma unroll
  for (int c = 0; c < NCLS; c++) { float v = hp[c]; s += v * sp[c]; d += v * dp[c]; }
  as[t] = s; ad[t] = d;
}

// ---------------- CSR build ----------------
__global__ __launch_bounds__(256) void hist_kernel(
    const int* __restrict__ ei, int* __restrict__ counts) {
  int e = blockIdx.x * 256 + threadIdx.x;
  if (e >= E_TOT) return;
  int dst = (e < N_EDGES) ? ei[N_EDGES + e] : (e - N_EDGES);
  atomicAdd(&counts[dst], 1);
}

__global__ __launch_bounds__(1024) void scan_kernel(
    const int* __restrict__ counts, int* __restrict__ offsets,
    int* __restrict__ fillpos) {
  __shared__ int part[1024];
  const int CH = (N_NODES + 1023) / 1024;  // 49
  int t = threadIdx.x;
  int begin = t * CH;
  int end = begin + CH; if (end > N_NODES) end = N_NODES;
  int s = 0;
  for (int i = begin; i < end; i++) s += counts[i];
  part[t] = s;
  __syncthreads();
  for (int o = 1; o < 1024; o <<= 1) {
    int v = (t >= o) ? part[t - o] : 0;
    __syncthreads();
    part[t] += v;
    __syncthreads();
  }
  int run = (t == 0) ? 0 : part[t - 1];
  for (int i = begin; i < end; i++) {
    offsets[i] = run; fillpos[i] = run;
    run += counts[i];
  }
  if (t == 1023) offsets[N_NODES] = part[1023];
}

__global__ __launch_bounds__(256) void fill_kernel(
    const int* __restrict__ ei, int* __restrict__ fillpos,
    int* __restrict__ csr_src) {
  int e = blockIdx.x * 256 + threadIdx.x;
  if (e >= E_TOT) return;
  int src, dst;
  if (e < N_EDGES) { src = ei[e]; dst = ei[N_EDGES + e]; }
  else { src = dst = e - N_EDGES; }
  int pos = atomicAdd(&fillpos[dst], 1);
  csr_src[pos] = src;
}

// ---------------- aggregation layer 1 (fused softmax + ELU) ----------------
// one wave per node; lane covers f=lane, f=lane+64
__global__ __launch_bounds__(256) void agg1_kernel(
    const float* __restrict__ h1, const float* __restrict__ as,
    const float* __restrict__ ad, const int* __restrict__ off,
    const int* __restrict__ csr, const float* __restrict__ b1,
    float* __restrict__ out) {
  int gw = (blockIdx.x * blockDim.x + threadIdx.x) >> 6;
  int lane = threadIdx.x & 63;
  if (gw >= N_NODES) return;
  int start = off[gw];
  int deg = off[gw + 1] - start;
  // pass 1: online softmax stats per head (16 lanes/head)
  int h = lane & 3;
  float adh = ad[gw * 4 + h];
  float m = -1e30f, s = 0.f;
  for (int j = lane >> 2; j < deg; j += 16) {
    int src = csr[start + j];
    float v = as[src * 4 + h] + adh;
    v = v > 0.f ? v : NEG * v;
    if (v > m) { s *= __expf(m - v); m = v; }
    s += __expf(v - m);
  }
#pragma unroll
  for (int o = 4; o < 64; o <<= 1) {
    float om = __shfl_xor(m, o), os = __shfl_xor(s, o);
    float nm = fmaxf(m, om);
    s = s * __expf(m - nm) + os * __expf(om - nm);
    m = nm;
  }
  // lane g (g<4) holds head g stats; redistribute to per-feature heads
  int g0 = lane >> 5;        // head of f=lane  (0..1)
  int g1 = 2 + (lane >> 5);  // head of f=lane+64 (2..3)
  float m0 = __shfl(m, g0), s0 = __shfl(s, g0);
  float m1 = __shfl(m, g1), s1 = __shfl(s, g1);
  float i0 = 1.f / s0, i1 = 1.f / s1;
  float ad0 = ad[gw * 4 + g0], ad1 = ad[gw * 4 + g1];
  float acc0 = 0.f, acc1 = 0.f;
  for (int j = 0; j < deg; j++) {
    int src = csr[start + j];
    const float* hrow = h1 + (size_t)src * F1;
    float e0 = as[src * 4 + g0] + ad0; e0 = e0 > 0.f ? e0 : NEG * e0;
    float e1 = as[src * 4 + g1] + ad1; e1 = e1 > 0.f ? e1 : NEG * e1;
    float w0 = __expf(e0 - m0) * i0;
    float w1 = __expf(e1 - m1) * i1;
    acc0 += w0 * hrow[lane];
    acc1 += w1 * hrow[64 + lane];
  }
  float o0 = acc0 + b1[lane];
  float o1 = acc1 + b1[64 + lane];
  o0 = o0 > 0.f ? o0 : expm1f(o0);   // ELU fused
  o1 = o1 > 0.f ? o1 : expm1f(o1);
  out[(size_t)gw * F1 + lane]      = o0;
  out[(size_t)gw * F1 + 64 + lane] = o1;
}

// ---------------- aggregation layer 2 ----------------
// one wave per node; lane covers f=lane, lane+64, lane+128(lane<32)
__global__ __launch_bounds__(256) void agg2_kernel(
    const float* __restrict__ h2, const float* __restrict__ as,
    const float* __restrict__ ad, const int* __restrict__ off,
    const int* __restrict__ csr, const float* __restrict__ b2,
    float* __restrict__ out) {
  int gw = (blockIdx.x * blockDim.x + threadIdx.x) >> 6;
  int lane = threadIdx.x & 63;
  if (gw >= N_NODES) return;
  int start = off[gw];
  int deg = off[gw + 1] - start;
  int h = lane & 3;
  float adh = ad[gw * 4 + h];
  float m = -1e30f, s = 0.f;
  for (int j = lane >> 2; j < deg; j += 16) {
    int src = csr[start + j];
    float v = as[src * 4 + h] + adh;
    v = v > 0.f ? v : NEG * v;
    if (v > m) { s *= __expf(m - v); m = v; }
    s += __expf(v - m);
  }
#pragma unroll
  for (int o = 4; o < 64; o <<= 1) {
    float om = __shfl_xor(m, o), os = __shfl_xor(s, o);
    float nm = fmaxf(m, om);
    s = s * __expf(m - nm) + os * __expf(om - nm);
    m = nm;
  }
  int g0 = lane / NCLS;          // head of f=lane
  int g1 = (lane + 64) / NCLS;   // head of f=lane+64
  int g2 = (lane + 128) / NCLS;  // head of f=lane+128
  float m0 = __shfl(m, g0), s0 = __shfl(s, g0);
  float m1 = __shfl(m, g1), s1 = __shfl(s, g1);
  float m2 = __shfl(m, g2), s2 = __shfl(s, g2);
  float i0 = 1.f / s0, i1 = 1.f / s1, i2 = 1.f / s2;
  float ad0 = ad[gw * 4 + g0], ad1 = ad[gw * 4 + g1], ad2 = ad[gw * 4 + g2];
  float acc0 = 0.f, acc1 = 0.f, acc2 = 0.f;
  bool third = lane < 32;
  for (int j = 0; j < deg; j++) {
    int src = csr[start + j];
    const float* hrow = h2 + (size_t)src * F2;
    float e0 = as[src * 4 + g0] + ad0; e0 = e0 > 0.f ? e0 : NEG * e0;
    float e1 = as[src * 4 + g1] + ad1; e1 = e1 > 0.f ? e1 : NEG * e1;
    float w0 = __expf(e0 - m0) * i0;
    float w1 = __expf(e1 - m1) * i1;
    acc0 += w0 * hrow[lane];
    acc1 += w1 * hrow[64 + lane];
    if (third) {
      float e2 = as[src * 4 + g2] + ad2; e2 = e2 > 0.f ? e2 : NEG * e2;
      acc2 += __expf(e2 - m2) * i2 * hrow[128 + lane];
    }
  }
  out[(size_t)gw * F2 + lane]      = acc0 + b2[lane];
  out[(size_t)gw * F2 + 64 + lane] = acc1 + b2[64 + lane];
  if (third) out[(size_t)gw * F2 + 128 + lane] = acc2 + b2[128 + lane];
}

extern "C" void kernel_launch(void* const* d_in, const int* in_sizes, int n_in,
                              void* d_out, int out_size, void* d_ws, size_t ws_size,
                              hipStream_t stream) {
  const float* x   = (const float*)d_in[0];
  const int*   ei  = (const int*)d_in[1];
  const float* bng = (const float*)d_in[2];
  const float* bnb = (const float*)d_in[3];
  const float* bnm = (const float*)d_in[4];
  const float* bnv = (const float*)d_in[5];
  const float* W1  = (const float*)d_in[6];
  const float* a1s = (const float*)d_in[7];
  const float* a1d = (const float*)d_in[8];
  const float* b1  = (const float*)d_in[9];
  const float* W2  = (const float*)d_in[10];
  const float* a2s = (const float*)d_in[11];
  const float* a2d = (const float*)d_in[12];
  const float* b2  = (const float*)d_in[13];
  float* out = (float*)d_out;

  char* ws = (char*)d_ws;
  size_t p = 0;
  auto alloc = [&](size_t bytes) -> char* {
    char* r = ws + p;
    p += (bytes + 255) & ~(size_t)255;
    return r;
  };
  float* h0   = (float*)alloc(sizeof(float) * (size_t)N_NODES * IN_F); // 25.8MB
  float* h1   = (float*)alloc(sizeof(float) * (size_t)N_NODES * F1);   // 25.6MB
  float* h1a  = (float*)alloc(sizeof(float) * (size_t)N_NODES * F1);   // 25.6MB
  float* as1  = (float*)alloc(sizeof(float) * (size_t)N_NODES * HEADS);
  float* ad1  = (float*)alloc(sizeof(float) * (size_t)N_NODES * HEADS);
  float* as2  = (float*)alloc(sizeof(float) * (size_t)N_NODES * HEADS);
  float* ad2  = (float*)alloc(sizeof(float) * (size_t)N_NODES * HEADS);
  int* counts = (int*)alloc(sizeof(int) * (N_NODES + 1));
  int* offs   = (int*)alloc(sizeof(int) * (N_NODES + 1));
  int* fpos   = (int*)alloc(sizeof(int) * N_NODES);
  int* csr    = (int*)alloc(sizeof(int) * E_TOT);
  // h2 [N,160] = 32MB aliases h0+start of h1 (both dead by gemm2 time)
  float* h2 = h0;

  hipMemsetAsync(counts, 0, sizeof(int) * (N_NODES + 1), stream);

  bn_kernel<<<(N_NODES * IN_F + 255) / 256, 256, 0, stream>>>(x, bng, bnb, bnm, bnv, h0);

  int gemm_waves = (N_NODES + 7) / 8;                  // 6250
  int gemm_blocks = (gemm_waves + 3) / 4;              // 1563
  gemm1_kernel<<<gemm_blocks, 256, 0, stream>>>(h0, W1, h1);
  alpha1_kernel<<<(N_NODES * HEADS + 255) / 256, 256, 0, stream>>>(h1, a1s, a1d, as1, ad1);

  hist_kernel<<<(E_TOT + 255) / 256, 256, 0, stream>>>(ei, counts);
  scan_kernel<<<1, 1024, 0, stream>>>(counts, offs, fpos);
  fill_kernel<<<(E_TOT + 255) / 256, 256, 0, stream>>>(ei, fpos, csr);

  agg1_kernel<<<(N_NODES + 3) / 4, 256, 0, stream>>>(h1, as1, ad1, offs, csr, b1, h1a);

  gemm2_kernel<<<gemm_blocks, 256, 0, stream>>>(h1a, W2, h2);
  alpha2_kernel<<<(N_NODES * HEADS + 255) / 256, 256, 0, stream>>>(h2, a2s, a2d, as2, ad2);

  agg2_kernel<<<(N_NODES + 3) / 4, 256, 0, stream>>>(h2, as2, ad2, offs, csr, b2, out);
}

// Round 2
// 567.497 us; speedup vs baseline: 1.2819x; 1.2819x over previous
//
#include <hip/hip_runtime.h>

#define N_NODES 50000
#define N_EDGES 800000
#define E_TOT   (N_EDGES + N_NODES)   // with self loops: 850000
#define IN_F    129
#define HID     32
#define HEADS   4
#define F1      (HEADS * HID)     // 128
#define NCLS    40
#define F2      (HEADS * NCLS)    // 160
#define NEG     0.2f
#define BN_EPS  1e-5f
#define PITCH1  132               // 129 padded to /4 alignment for float4 LDS reads

// ---------------- GEMM1 (BN fused): [N,129] x [129,128] ----------------
// block = 256 thr = 4 waves; 32 nodes/block staged in LDS; wave computes 8 nodes
__global__ __launch_bounds__(256) void gemm1_kernel(
    const float* __restrict__ x,
    const float* __restrict__ bng, const float* __restrict__ bnb,
    const float* __restrict__ bnm, const float* __restrict__ bnv,
    const float* __restrict__ W, float* __restrict__ h1) {
  __shared__ float scale[IN_F], shift[IN_F];
  __shared__ float rows[32 * PITCH1];
  int tid = threadIdx.x;
  if (tid < IN_F) {
    float sc = bng[tid] * rsqrtf(bnv[tid] + BN_EPS);
    scale[tid] = sc;
    shift[tid] = bnb[tid] - bnm[tid] * sc;
  }
  __syncthreads();
  int nb = blockIdx.x * 32;
  int nvalid = N_NODES - nb; if (nvalid > 32) nvalid = 32;
  const float* xb = x + (size_t)nb * IN_F;
  int total = nvalid * IN_F;
  for (int i = tid; i < total; i += 256) {
    int r = i / IN_F;
    int c = i - r * IN_F;
    rows[r * PITCH1 + c] = xb[i] * scale[c] + shift[c];
  }
  __syncthreads();
  int wave = tid >> 6, lane = tid & 63;
  int r0 = wave * 8;
  if (r0 >= nvalid) return;
  const float* rp[8];
#pragma unroll
  for (int i = 0; i < 8; i++) {
    int ri = r0 + i; if (ri >= nvalid) ri = nvalid - 1;
    rp[i] = &rows[ri * PITCH1];
  }
  float a0[8] = {}, a1[8] = {};
  for (int k = 0; k < 128; k += 4) {
    float4 xv[8];
#pragma unroll
    for (int i = 0; i < 8; i++) xv[i] = *(const float4*)(rp[i] + k);
    float w00 = W[(k+0)*F1 + lane],      w10 = W[(k+0)*F1 + 64 + lane];
    float w01 = W[(k+1)*F1 + lane],      w11 = W[(k+1)*F1 + 64 + lane];
    float w02 = W[(k+2)*F1 + lane],      w12 = W[(k+2)*F1 + 64 + lane];
    float w03 = W[(k+3)*F1 + lane],      w13 = W[(k+3)*F1 + 64 + lane];
#pragma unroll
    for (int i = 0; i < 8; i++) {
      a0[i] += xv[i].x*w00 + xv[i].y*w01 + xv[i].z*w02 + xv[i].w*w03;
      a1[i] += xv[i].x*w10 + xv[i].y*w11 + xv[i].z*w12 + xv[i].w*w13;
    }
  }
  { // k = 128 remainder
    float w0 = W[128*F1 + lane], w1 = W[128*F1 + 64 + lane];
#pragma unroll
    for (int i = 0; i < 8; i++) { float xk = rp[i][128]; a0[i] += xk*w0; a1[i] += xk*w1; }
  }
#pragma unroll
  for (int i = 0; i < 8; i++) {
    if (r0 + i >= nvalid) break;
    size_t n = nb + r0 + i;
    h1[n * F1 + lane]      = a0[i];
    h1[n * F1 + 64 + lane] = a1[i];
  }
}

// ---------------- GEMM2: [N,128] x [128,160] ----------------
__global__ __launch_bounds__(256) void gemm2_kernel(
    const float* __restrict__ hin, const float* __restrict__ W,
    float* __restrict__ hout) {
  __shared__ float rows[32 * F1];   // 16 KB, pitch==128 (aligned)
  int tid = threadIdx.x;
  int nb = blockIdx.x * 32;
  int nvalid = N_NODES - nb; if (nvalid > 32) nvalid = 32;
  const float4* src4 = (const float4*)(hin + (size_t)nb * F1);
  float4* dst4 = (float4*)rows;
  int tot4 = nvalid * (F1 / 4);
  for (int i = tid; i < tot4; i += 256) dst4[i] = src4[i];
  __syncthreads();
  int wave = tid >> 6, lane = tid & 63;
  int r0 = wave * 8;
  if (r0 >= nvalid) return;
  const float* rp[8];
#pragma unroll
  for (int i = 0; i < 8; i++) {
    int ri = r0 + i; if (ri >= nvalid) ri = nvalid - 1;
    rp[i] = &rows[ri * F1];
  }
  bool third = lane < 32;
  float a0[8] = {}, a1[8] = {}, a2[8] = {};
  for (int k = 0; k < F1; k += 4) {
    float4 xv[8];
#pragma unroll
    for (int i = 0; i < 8; i++) xv[i] = *(const float4*)(rp[i] + k);
    float w00 = W[(k+0)*F2 + lane], w10 = W[(k+0)*F2 + 64 + lane];
    float w01 = W[(k+1)*F2 + lane], w11 = W[(k+1)*F2 + 64 + lane];
    float w02 = W[(k+2)*F2 + lane], w12 = W[(k+2)*F2 + 64 + lane];
    float w03 = W[(k+3)*F2 + lane], w13 = W[(k+3)*F2 + 64 + lane];
    float w20 = third ? W[(k+0)*F2 + 128 + lane] : 0.f;
    float w21 = third ? W[(k+1)*F2 + 128 + lane] : 0.f;
    float w22 = third ? W[(k+2)*F2 + 128 + lane] : 0.f;
    float w23 = third ? W[(k+3)*F2 + 128 + lane] : 0.f;
#pragma unroll
    for (int i = 0; i < 8; i++) {
      a0[i] += xv[i].x*w00 + xv[i].y*w01 + xv[i].z*w02 + xv[i].w*w03;
      a1[i] += xv[i].x*w10 + xv[i].y*w11 + xv[i].z*w12 + xv[i].w*w13;
      a2[i] += xv[i].x*w20 + xv[i].y*w21 + xv[i].z*w22 + xv[i].w*w23;
    }
  }
#pragma unroll
  for (int i = 0; i < 8; i++) {
    if (r0 + i >= nvalid) break;
    size_t n = nb + r0 + i;
    hout[n * F2 + lane]      = a0[i];
    hout[n * F2 + 64 + lane] = a1[i];
    if (third) hout[n * F2 + 128 + lane] = a2[i];
  }
}

// ---------------- attention scalars ----------------
__global__ __launch_bounds__(256) void alpha1_kernel(
    const float* __restrict__ h1, const float* __restrict__ a_src,
    const float* __restrict__ a_dst, float* __restrict__ as,
    float* __restrict__ ad) {
  int t = blockIdx.x * 256 + threadIdx.x;
  if (t >= N_NODES * HEADS) return;
  int n = t >> 2, h = t & 3;
  const float* hp = h1 + (size_t)n * F1 + h * HID;
  const float* sp = a_src + h * HID;
  const float* dp = a_dst + h * HID;
  float s = 0.f, d = 0.f;
#pragma unroll
  for (int c = 0; c < HID; c++) { float v = hp[c]; s += v * sp[c]; d += v * dp[c]; }
  as[t] = s; ad[t] = d;
}

__global__ __launch_bounds__(256) void alpha2_kernel(
    const float* __restrict__ h2, const float* __restrict__ a_src,
    const float* __restrict__ a_dst, float* __restrict__ as,
    float* __restrict__ ad) {
  int t = blockIdx.x * 256 + threadIdx.x;
  if (t >= N_NODES * HEADS) return;
  int n = t >> 2, h = t & 3;
  const float* hp = h2 + (size_t)n * F2 + h * NCLS;
  const float* sp = a_src + h * NCLS;
  const float* dp = a_dst + h * NCLS;
  float s = 0.f, d = 0.f;
#pragma unroll
  for (int c = 0; c < NCLS; c++) { float v = hp[c]; s += v * sp[c]; d += v * dp[c]; }
  as[t] = s; ad[t] = d;
}

// ---------------- CSR build ----------------
__global__ __launch_bounds__(256) void hist_kernel(
    const int* __restrict__ ei, int* __restrict__ counts) {
  int e = blockIdx.x * 256 + threadIdx.x;
  if (e >= E_TOT) return;
  int dst = (e < N_EDGES) ? ei[N_EDGES + e] : (e - N_EDGES);
  atomicAdd(&counts[dst], 1);
}

__global__ __launch_bounds__(1024) void scan_kernel(
    const int* __restrict__ counts, int* __restrict__ offsets,
    int* __restrict__ fillpos) {
  __shared__ int part[1024];
  const int CH = (N_NODES + 1023) / 1024;  // 49
  int t = threadIdx.x;
  int begin = t * CH;
  int end = begin + CH; if (end > N_NODES) end = N_NODES;
  if (begin > N_NODES) begin = N_NODES;
  int s = 0;
  for (int i = begin; i < end; i++) s += counts[i];
  part[t] = s;
  __syncthreads();
  for (int o = 1; o < 1024; o <<= 1) {
    int v = (t >= o) ? part[t - o] : 0;
    __syncthreads();
    part[t] += v;
    __syncthreads();
  }
  int run = (t == 0) ? 0 : part[t - 1];
  for (int i = begin; i < end; i++) {
    offsets[i] = run; fillpos[i] = run;
    run += counts[i];
  }
  if (t == 1023) offsets[N_NODES] = part[1023];
}

__global__ __launch_bounds__(256) void fill_kernel(
    const int* __restrict__ ei, int* __restrict__ fillpos,
    int* __restrict__ csr_src) {
  int e = blockIdx.x * 256 + threadIdx.x;
  if (e >= E_TOT) return;
  int src, dst;
  if (e < N_EDGES) { src = ei[e]; dst = ei[N_EDGES + e]; }
  else { src = dst = e - N_EDGES; }
  int pos = atomicAdd(&fillpos[dst], 1);
  csr_src[pos] = src;
}

// ---------------- aggregation layer 1: single-pass online softmax + ELU ----
// one wave per node; lane covers f=lane, f=lane+64
__global__ __launch_bounds__(256) void agg1_kernel(
    const float* __restrict__ h1, const float* __restrict__ as,
    const float* __restrict__ ad, const int* __restrict__ off,
    const int* __restrict__ csr, const float* __restrict__ b1,
    float* __restrict__ out) {
  int gw = (blockIdx.x * blockDim.x + threadIdx.x) >> 6;
  int lane = threadIdx.x & 63;
  if (gw >= N_NODES) return;
  int base = off[gw];
  int deg  = off[gw + 1] - base;
  int g0 = lane >> 5;        // head of f=lane     (0..1)
  int g1 = 2 + (lane >> 5);  // head of f=lane+64  (2..3)
  float ad0 = ad[gw * 4 + g0], ad1 = ad[gw * 4 + g1];
  float m0 = -1e30f, m1 = -1e30f, s0 = 0.f, s1 = 0.f, acc0 = 0.f, acc1 = 0.f;
  int j = 0;
  for (; j + 4 <= deg; j += 4) {
    int sr[4];
#pragma unroll
    for (int u = 0; u < 4; u++) sr[u] = csr[base + j + u];
    float e0[4], e1[4], x0[4], x1[4];
#pragma unroll
    for (int u = 0; u < 4; u++) { e0[u] = as[sr[u]*4 + g0]; e1[u] = as[sr[u]*4 + g1]; }
#pragma unroll
    for (int u = 0; u < 4; u++) {
      const float* r = h1 + (size_t)sr[u] * F1;
      x0[u] = r[lane]; x1[u] = r[64 + lane];
    }
#pragma unroll
    for (int u = 0; u < 4; u++) {
      float v0 = e0[u] + ad0; v0 = v0 > 0.f ? v0 : NEG * v0;
      float v1 = e1[u] + ad1; v1 = v1 > 0.f ? v1 : NEG * v1;
      float n0 = fmaxf(m0, v0), n1 = fmaxf(m1, v1);
      float sc0 = __expf(m0 - n0), sc1 = __expf(m1 - n1);
      float w0 = __expf(v0 - n0), w1 = __expf(v1 - n1);
      s0 = s0 * sc0 + w0;            s1 = s1 * sc1 + w1;
      acc0 = acc0 * sc0 + w0 * x0[u]; acc1 = acc1 * sc1 + w1 * x1[u];
      m0 = n0; m1 = n1;
    }
  }
  for (; j < deg; j++) {
    int src = csr[base + j];
    float v0 = as[src*4 + g0] + ad0; v0 = v0 > 0.f ? v0 : NEG * v0;
    float v1 = as[src*4 + g1] + ad1; v1 = v1 > 0.f ? v1 : NEG * v1;
    const float* r = h1 + (size_t)src * F1;
    float x0 = r[lane], x1 = r[64 + lane];
    float n0 = fmaxf(m0, v0), n1 = fmaxf(m1, v1);
    float sc0 = __expf(m0 - n0), sc1 = __expf(m1 - n1);
    float w0 = __expf(v0 - n0), w1 = __expf(v1 - n1);
    s0 = s0 * sc0 + w0;            s1 = s1 * sc1 + w1;
    acc0 = acc0 * sc0 + w0 * x0;   acc1 = acc1 * sc1 + w1 * x1;
    m0 = n0; m1 = n1;
  }
  float o0 = acc0 / s0 + b1[lane];
  float o1 = acc1 / s1 + b1[64 + lane];
  o0 = o0 > 0.f ? o0 : expm1f(o0);   // ELU fused
  o1 = o1 > 0.f ? o1 : expm1f(o1);
  out[(size_t)gw * F1 + lane]      = o0;
  out[(size_t)gw * F1 + 64 + lane] = o1;
}

// ---------------- aggregation layer 2: single-pass online softmax ----------
// one wave per node; lane covers f=lane, lane+64, lane+128(lane<32)
__global__ __launch_bounds__(256) void agg2_kernel(
    const float* __restrict__ h2, const float* __restrict__ as,
    const float* __restrict__ ad, const int* __restrict__ off,
    const int* __restrict__ csr, const float* __restrict__ b2,
    float* __restrict__ out) {
  int gw = (blockIdx.x * blockDim.x + threadIdx.x) >> 6;
  int lane = threadIdx.x & 63;
  if (gw >= N_NODES) return;
  int base = off[gw];
  int deg  = off[gw + 1] - base;
  int g0 = lane / NCLS;           // 0..1
  int g1 = (lane + 64) / NCLS;    // 1..3
  int g2 = (lane + 128) / NCLS;   // 3 (lane<32)
  bool third = lane < 32;
  float ad0 = ad[gw*4 + g0], ad1 = ad[gw*4 + g1], ad2 = ad[gw*4 + g2];
  float m0 = -1e30f, m1 = -1e30f, m2 = -1e30f;
  float s0 = 0.f, s1 = 0.f, s2 = 0.f;
  float acc0 = 0.f, acc1 = 0.f, acc2 = 0.f;
  int j = 0;
  for (; j + 4 <= deg; j += 4) {
    int sr[4];
#pragma unroll
    for (int u = 0; u < 4; u++) sr[u] = csr[base + j + u];
    float e0[4], e1[4], e2[4], x0[4], x1[4], x2[4];
#pragma unroll
    for (int u = 0; u < 4; u++) {
      e0[u] = as[sr[u]*4 + g0]; e1[u] = as[sr[u]*4 + g1]; e2[u] = as[sr[u]*4 + g2];
    }
#pragma unroll
    for (int u = 0; u < 4; u++) {
      const float* r = h2 + (size_t)sr[u] * F2;
      x0[u] = r[lane]; x1[u] = r[64 + lane];
      x2[u] = third ? r[128 + lane] : 0.f;
    }
#pragma unroll
    for (int u = 0; u < 4; u++) {
      float v0 = e0[u] + ad0; v0 = v0 > 0.f ? v0 : NEG * v0;
      float v1 = e1[u] + ad1; v1 = v1 > 0.f ? v1 : NEG * v1;
      float v2 = e2[u] + ad2; v2 = v2 > 0.f ? v2 : NEG * v2;
      float n0 = fmaxf(m0, v0), n1 = fmaxf(m1, v1), n2 = fmaxf(m2, v2);
      float sc0 = __expf(m0 - n0), sc1 = __expf(m1 - n1), sc2 = __expf(m2 - n2);
      float w0 = __expf(v0 - n0), w1 = __expf(v1 - n1), w2 = __expf(v2 - n2);
      s0 = s0*sc0 + w0; s1 = s1*sc1 + w1; s2 = s2*sc2 + w2;
      acc0 = acc0*sc0 + w0*x0[u]; acc1 = acc1*sc1 + w1*x1[u]; acc2 = acc2*sc2 + w2*x2[u];
      m0 = n0; m1 = n1; m2 = n2;
    }
  }
  for (; j < deg; j++) {
    int src = csr[base + j];
    float v0 = as[src*4 + g0] + ad0; v0 = v0 > 0.f ? v0 : NEG * v0;
    float v1 = as[src*4 + g1] + ad1; v1 = v1 > 0.f ? v1 : NEG * v1;
    float v2 = as[src*4 + g2] + ad2; v2 = v2 > 0.f ? v2 : NEG * v2;
    const float* r = h2 + (size_t)src * F2;
    float x0 = r[lane], x1 = r[64 + lane];
    float x2 = third ? r[128 + lane] : 0.f;
    float n0 = fmaxf(m0, v0), n1 = fmaxf(m1, v1), n2 = fmaxf(m2, v2);
    float sc0 = __expf(m0 - n0), sc1 = __expf(m1 - n1), sc2 = __expf(m2 - n2);
    float w0 = __expf(v0 - n0), w1 = __expf(v1 - n1), w2 = __expf(v2 - n2);
    s0 = s0*sc0 + w0; s1 = s1*sc1 + w1; s2 = s2*sc2 + w2;
    acc0 = acc0*sc0 + w0*x0; acc1 = acc1*sc1 + w1*x1; acc2 = acc2*sc2 + w2*x2;
    m0 = n0; m1 = n1; m2 = n2;
  }
  out[(size_t)gw * F2 + lane]      = acc0/s0 + b2[lane];
  out[(size_t)gw * F2 + 64 + lane] = acc1/s1 + b2[64 + lane];
  if (third) out[(size_t)gw * F2 + 128 + lane] = acc2/s2 + b2[128 + lane];
}

extern "C" void kernel_launch(void* const* d_in, const int* in_sizes, int n_in,
                              void* d_out, int out_size, void* d_ws, size_t ws_size,
                              hipStream_t stream) {
  const float* x   = (const float*)d_in[0];
  const int*   ei  = (const int*)d_in[1];
  const float* bng = (const float*)d_in[2];
  const float* bnb = (const float*)d_in[3];
  const float* bnm = (const float*)d_in[4];
  const float* bnv = (const float*)d_in[5];
  const float* W1  = (const float*)d_in[6];
  const float* a1s = (const float*)d_in[7];
  const float* a1d = (const float*)d_in[8];
  const float* b1  = (const float*)d_in[9];
  const float* W2  = (const float*)d_in[10];
  const float* a2s = (const float*)d_in[11];
  const float* a2d = (const float*)d_in[12];
  const float* b2  = (const float*)d_in[13];
  float* out = (float*)d_out;

  char* ws = (char*)d_ws;
  size_t p = 0;
  auto alloc = [&](size_t bytes) -> char* {
    char* r = ws + p;
    p += (bytes + 255) & ~(size_t)255;
    return r;
  };
  float* h1   = (float*)alloc(sizeof(float) * (size_t)N_NODES * F1);   // 25.6MB
  float* h1a  = (float*)alloc(sizeof(float) * (size_t)N_NODES * F1);   // 25.6MB
  float* h2   = (float*)alloc(sizeof(float) * (size_t)N_NODES * F2);   // 32MB
  float* as1  = (float*)alloc(sizeof(float) * (size_t)N_NODES * HEADS);
  float* ad1  = (float*)alloc(sizeof(float) * (size_t)N_NODES * HEADS);
  float* as2  = (float*)alloc(sizeof(float) * (size_t)N_NODES * HEADS);
  float* ad2  = (float*)alloc(sizeof(float) * (size_t)N_NODES * HEADS);
  int* counts = (int*)alloc(sizeof(int) * (N_NODES + 1));
  int* offs   = (int*)alloc(sizeof(int) * (N_NODES + 1));
  int* fpos   = (int*)alloc(sizeof(int) * N_NODES);
  int* csr    = (int*)alloc(sizeof(int) * E_TOT);

  hipMemsetAsync(counts, 0, sizeof(int) * (N_NODES + 1), stream);

  // CSR build
  hist_kernel<<<(E_TOT + 255) / 256, 256, 0, stream>>>(ei, counts);
  scan_kernel<<<1, 1024, 0, stream>>>(counts, offs, fpos);
  fill_kernel<<<(E_TOT + 255) / 256, 256, 0, stream>>>(ei, fpos, csr);

  // layer 1
  int gblocks = (N_NODES + 31) / 32;   // 1563
  gemm1_kernel<<<gblocks, 256, 0, stream>>>(x, bng, bnb, bnm, bnv, W1, h1);
  alpha1_kernel<<<(N_NODES * HEADS + 255) / 256, 256, 0, stream>>>(h1, a1s, a1d, as1, ad1);
  agg1_kernel<<<(N_NODES + 3) / 4, 256, 0, stream>>>(h1, as1, ad1, offs, csr, b1, h1a);

  // layer 2
  gemm2_kernel<<<gblocks, 256, 0, stream>>>(h1a, W2, h2);
  alpha2_kernel<<<(N_NODES * HEADS + 255) / 256, 256, 0, stream>>>(h2, a2s, a2d, as2, ad2);
  agg2_kernel<<<(N_NODES + 3) / 4, 256, 0, stream>>>(h2, as2, ad2, offs, csr, b2, out);
}

// Round 4
// 468.641 us; speedup vs baseline: 1.5523x; 1.2109x over previous
//
#include <hip/hip_runtime.h>

#define N_NODES 50000
#define N_EDGES 800000
#define E_TOT   (N_EDGES + N_NODES)   // with self loops: 850000
#define IN_F    129
#define HID     32
#define HEADS   4
#define F1      (HEADS * HID)     // 128
#define NCLS    40
#define F2      (HEADS * NCLS)    // 160
#define NEG     0.2f
#define BN_EPS  1e-5f
#define PITCH1  132               // 129 padded to /4 alignment for float4 LDS reads
#define SCAN_NB ((N_NODES + 255) / 256)   // 196

// ---------------- GEMM1 (BN fused): [N,129] x [129,128] ----------------
__global__ __launch_bounds__(256) void gemm1_kernel(
    const float* __restrict__ x,
    const float* __restrict__ bng, const float* __restrict__ bnb,
    const float* __restrict__ bnm, const float* __restrict__ bnv,
    const float* __restrict__ W, float* __restrict__ h1) {
  __shared__ float scale[IN_F], shift[IN_F];
  __shared__ float rows[32 * PITCH1];
  int tid = threadIdx.x;
  if (tid < IN_F) {
    float sc = bng[tid] * rsqrtf(bnv[tid] + BN_EPS);
    scale[tid] = sc;
    shift[tid] = bnb[tid] - bnm[tid] * sc;
  }
  __syncthreads();
  int nb = blockIdx.x * 32;
  int nvalid = N_NODES - nb; if (nvalid > 32) nvalid = 32;
  const float* xb = x + (size_t)nb * IN_F;
  int total = nvalid * IN_F;
  for (int i = tid; i < total; i += 256) {
    int r = i / IN_F;
    int c = i - r * IN_F;
    rows[r * PITCH1 + c] = xb[i] * scale[c] + shift[c];
  }
  __syncthreads();
  int wave = tid >> 6, lane = tid & 63;
  int r0 = wave * 8;
  if (r0 >= nvalid) return;
  const float* rp[8];
#pragma unroll
  for (int i = 0; i < 8; i++) {
    int ri = r0 + i; if (ri >= nvalid) ri = nvalid - 1;
    rp[i] = &rows[ri * PITCH1];
  }
  float a0[8] = {}, a1[8] = {};
  for (int k = 0; k < 128; k += 4) {
    float4 xv[8];
#pragma unroll
    for (int i = 0; i < 8; i++) xv[i] = *(const float4*)(rp[i] + k);
    float w00 = W[(k+0)*F1 + lane],      w10 = W[(k+0)*F1 + 64 + lane];
    float w01 = W[(k+1)*F1 + lane],      w11 = W[(k+1)*F1 + 64 + lane];
    float w02 = W[(k+2)*F1 + lane],      w12 = W[(k+2)*F1 + 64 + lane];
    float w03 = W[(k+3)*F1 + lane],      w13 = W[(k+3)*F1 + 64 + lane];
#pragma unroll
    for (int i = 0; i < 8; i++) {
      a0[i] += xv[i].x*w00 + xv[i].y*w01 + xv[i].z*w02 + xv[i].w*w03;
      a1[i] += xv[i].x*w10 + xv[i].y*w11 + xv[i].z*w12 + xv[i].w*w13;
    }
  }
  { // k = 128 remainder
    float w0 = W[128*F1 + lane], w1 = W[128*F1 + 64 + lane];
#pragma unroll
    for (int i = 0; i < 8; i++) { float xk = rp[i][128]; a0[i] += xk*w0; a1[i] += xk*w1; }
  }
#pragma unroll
  for (int i = 0; i < 8; i++) {
    if (r0 + i >= nvalid) break;
    size_t n = nb + r0 + i;
    h1[n * F1 + lane]      = a0[i];
    h1[n * F1 + 64 + lane] = a1[i];
  }
}

// ---------------- GEMM2: [N,128] x [128,160] ----------------
__global__ __launch_bounds__(256) void gemm2_kernel(
    const float* __restrict__ hin, const float* __restrict__ W,
    float* __restrict__ hout) {
  __shared__ float rows[32 * F1];   // 16 KB
  int tid = threadIdx.x;
  int nb = blockIdx.x * 32;
  int nvalid = N_NODES - nb; if (nvalid > 32) nvalid = 32;
  const float4* src4 = (const float4*)(hin + (size_t)nb * F1);
  float4* dst4 = (float4*)rows;
  int tot4 = nvalid * (F1 / 4);
  for (int i = tid; i < tot4; i += 256) dst4[i] = src4[i];
  __syncthreads();
  int wave = tid >> 6, lane = tid & 63;
  int r0 = wave * 8;
  if (r0 >= nvalid) return;
  const float* rp[8];
#pragma unroll
  for (int i = 0; i < 8; i++) {
    int ri = r0 + i; if (ri >= nvalid) ri = nvalid - 1;
    rp[i] = &rows[ri * F1];
  }
  bool third = lane < 32;
  float a0[8] = {}, a1[8] = {}, a2[8] = {};
  for (int k = 0; k < F1; k += 4) {
    float4 xv[8];
#pragma unroll
    for (int i = 0; i < 8; i++) xv[i] = *(const float4*)(rp[i] + k);
    float w00 = W[(k+0)*F2 + lane], w10 = W[(k+0)*F2 + 64 + lane];
    float w01 = W[(k+1)*F2 + lane], w11 = W[(k+1)*F2 + 64 + lane];
    float w02 = W[(k+2)*F2 + lane], w12 = W[(k+2)*F2 + 64 + lane];
    float w03 = W[(k+3)*F2 + lane], w13 = W[(k+3)*F2 + 64 + lane];
    float w20 = third ? W[(k+0)*F2 + 128 + lane] : 0.f;
    float w21 = third ? W[(k+1)*F2 + 128 + lane] : 0.f;
    float w22 = third ? W[(k+2)*F2 + 128 + lane] : 0.f;
    float w23 = third ? W[(k+3)*F2 + 128 + lane] : 0.f;
#pragma unroll
    for (int i = 0; i < 8; i++) {
      a0[i] += xv[i].x*w00 + xv[i].y*w01 + xv[i].z*w02 + xv[i].w*w03;
      a1[i] += xv[i].x*w10 + xv[i].y*w11 + xv[i].z*w12 + xv[i].w*w13;
      a2[i] += xv[i].x*w20 + xv[i].y*w21 + xv[i].z*w22 + xv[i].w*w23;
    }
  }
#pragma unroll
  for (int i = 0; i < 8; i++) {
    if (r0 + i >= nvalid) break;
    size_t n = nb + r0 + i;
    hout[n * F2 + lane]      = a0[i];
    hout[n * F2 + 64 + lane] = a1[i];
    if (third) hout[n * F2 + 128 + lane] = a2[i];
  }
}

// ---------------- attention scalars ----------------
__global__ __launch_bounds__(256) void alpha1_kernel(
    const float* __restrict__ h1, const float* __restrict__ a_src,
    const float* __restrict__ a_dst, float* __restrict__ as,
    float* __restrict__ ad) {
  int t = blockIdx.x * 256 + threadIdx.x;
  if (t >= N_NODES * HEADS) return;
  int n = t >> 2, h = t & 3;
  const float* hp = h1 + (size_t)n * F1 + h * HID;
  const float* sp = a_src + h * HID;
  const float* dp = a_dst + h * HID;
  float s = 0.f, d = 0.f;
#pragma unroll
  for (int c = 0; c < HID; c++) { float v = hp[c]; s += v * sp[c]; d += v * dp[c]; }
  as[t] = s; ad[t] = d;
}

__global__ __launch_bounds__(256) void alpha2_kernel(
    const float* __restrict__ h2, const float* __restrict__ a_src,
    const float* __restrict__ a_dst, float* __restrict__ as,
    float* __restrict__ ad) {
  int t = blockIdx.x * 256 + threadIdx.x;
  if (t >= N_NODES * HEADS) return;
  int n = t >> 2, h = t & 3;
  const float* hp = h2 + (size_t)n * F2 + h * NCLS;
  const float* sp = a_src + h * NCLS;
  const float* dp = a_dst + h * NCLS;
  float s = 0.f, d = 0.f;
#pragma unroll
  for (int c = 0; c < NCLS; c++) { float v = hp[c]; s += v * sp[c]; d += v * dp[c]; }
  as[t] = s; ad[t] = d;
}

// ---------------- CSR build ----------------
__global__ __launch_bounds__(256) void hist_kernel(
    const int* __restrict__ ei, int* __restrict__ counts) {
  int e = blockIdx.x * 256 + threadIdx.x;
  if (e >= E_TOT) return;
  int dst = (e < N_EDGES) ? ei[N_EDGES + e] : (e - N_EDGES);
  atomicAdd(&counts[dst], 1);
}

// two-level scan: partial sums -> scan of block sums -> scatter
__global__ __launch_bounds__(256) void partial_kernel(
    const int* __restrict__ counts, int* __restrict__ bsum) {
  __shared__ int red[4];
  int i = blockIdx.x * 256 + threadIdx.x;
  int v = (i < N_NODES) ? counts[i] : 0;
#pragma unroll
  for (int o = 1; o < 64; o <<= 1) v += __shfl_xor(v, o);
  int lane = threadIdx.x & 63, wave = threadIdx.x >> 6;
  if (lane == 0) red[wave] = v;
  __syncthreads();
  if (threadIdx.x == 0) bsum[blockIdx.x] = red[0] + red[1] + red[2] + red[3];
}

__global__ __launch_bounds__(256) void bscan_kernel(
    const int* __restrict__ bsum, int* __restrict__ bpre) {
  __shared__ int sh[256];
  int t = threadIdx.x;
  int v = (t < SCAN_NB) ? bsum[t] : 0;
  sh[t] = v;
  __syncthreads();
  for (int o = 1; o < 256; o <<= 1) {
    int u = (t >= o) ? sh[t - o] : 0;
    __syncthreads();
    sh[t] += u;
    __syncthreads();
  }
  if (t < SCAN_NB) bpre[t] = sh[t] - v;   // exclusive
}

__global__ __launch_bounds__(256) void scatter_kernel(
    const int* __restrict__ counts, const int* __restrict__ bpre,
    int* __restrict__ offsets, int* __restrict__ fillpos) {
  __shared__ int sh[256];
  int t = threadIdx.x;
  int i = blockIdx.x * 256 + t;
  int v = (i < N_NODES) ? counts[i] : 0;
  sh[t] = v;
  __syncthreads();
  for (int o = 1; o < 256; o <<= 1) {
    int u = (t >= o) ? sh[t - o] : 0;
    __syncthreads();
    sh[t] += u;
    __syncthreads();
  }
  if (i < N_NODES) {
    int excl = bpre[blockIdx.x] + sh[t] - v;
    offsets[i] = excl;
    fillpos[i] = excl;
  }
  if (i == 0) offsets[N_NODES] = E_TOT;
}

__global__ __launch_bounds__(256) void fill_kernel(
    const int* __restrict__ ei, int* __restrict__ fillpos,
    int* __restrict__ csr_src) {
  int e = blockIdx.x * 256 + threadIdx.x;
  if (e >= E_TOT) return;
  int src, dst;
  if (e < N_EDGES) { src = ei[e]; dst = ei[N_EDGES + e]; }
  else { src = dst = e - N_EDGES; }
  int pos = atomicAdd(&fillpos[dst], 1);
  csr_src[pos] = src;
}

// ---------------- aggregation layer 1: single-pass online softmax + ELU ----
__global__ __launch_bounds__(256) void agg1_kernel(
    const float* __restrict__ h1, const float* __restrict__ as,
    const float* __restrict__ ad, const int* __restrict__ off,
    const int* __restrict__ csr, const float* __restrict__ b1,
    float* __restrict__ out) {
  int gw = (blockIdx.x * blockDim.x + threadIdx.x) >> 6;
  int lane = threadIdx.x & 63;
  if (gw >= N_NODES) return;
  int base = off[gw];
  int deg  = off[gw + 1] - base;
  int g0 = lane >> 5;        // head of f=lane     (0..1)
  int g1 = 2 + (lane >> 5);  // head of f=lane+64  (2..3)
  float ad0 = ad[gw * 4 + g0], ad1 = ad[gw * 4 + g1];
  float m0 = -1e30f, m1 = -1e30f, s0 = 0.f, s1 = 0.f, acc0 = 0.f, acc1 = 0.f;
  int j = 0;
  for (; j + 4 <= deg; j += 4) {
    int sr[4];
#pragma unroll
    for (int u = 0; u < 4; u++) sr[u] = csr[base + j + u];
    float e0[4], e1[4], x0[4], x1[4];
#pragma unroll
    for (int u = 0; u < 4; u++) { e0[u] = as[sr[u]*4 + g0]; e1[u] = as[sr[u]*4 + g1]; }
#pragma unroll
    for (int u = 0; u < 4; u++) {
      const float* r = h1 + (size_t)sr[u] * F1;
      x0[u] = r[lane]; x1[u] = r[64 + lane];
    }
#pragma unroll
    for (int u = 0; u < 4; u++) {
      float v0 = e0[u] + ad0; v0 = v0 > 0.f ? v0 : NEG * v0;
      float v1 = e1[u] + ad1; v1 = v1 > 0.f ? v1 : NEG * v1;
      float n0 = fmaxf(m0, v0), n1 = fmaxf(m1, v1);
      float sc0 = __expf(m0 - n0), sc1 = __expf(m1 - n1);
      float w0 = __expf(v0 - n0), w1 = __expf(v1 - n1);
      s0 = s0 * sc0 + w0;            s1 = s1 * sc1 + w1;
      acc0 = acc0 * sc0 + w0 * x0[u]; acc1 = acc1 * sc1 + w1 * x1[u];
      m0 = n0; m1 = n1;
    }
  }
  for (; j < deg; j++) {
    int src = csr[base + j];
    float v0 = as[src*4 + g0] + ad0; v0 = v0 > 0.f ? v0 : NEG * v0;
    float v1 = as[src*4 + g1] + ad1; v1 = v1 > 0.f ? v1 : NEG * v1;
    const float* r = h1 + (size_t)src * F1;
    float x0 = r[lane], x1 = r[64 + lane];
    float n0 = fmaxf(m0, v0), n1 = fmaxf(m1, v1);
    float sc0 = __expf(m0 - n0), sc1 = __expf(m1 - n1);
    float w0 = __expf(v0 - n0), w1 = __expf(v1 - n1);
    s0 = s0 * sc0 + w0;            s1 = s1 * sc1 + w1;
    acc0 = acc0 * sc0 + w0 * x0;   acc1 = acc1 * sc1 + w1 * x1;
    m0 = n0; m1 = n1;
  }
  float o0 = acc0 / s0 + b1[lane];
  float o1 = acc1 / s1 + b1[64 + lane];
  o0 = o0 > 0.f ? o0 : expm1f(o0);   // ELU fused
  o1 = o1 > 0.f ? o1 : expm1f(o1);
  out[(size_t)gw * F1 + lane]      = o0;
  out[(size_t)gw * F1 + 64 + lane] = o1;
}

// ---------------- aggregation layer 2: single-pass online softmax ----------
__global__ __launch_bounds__(256) void agg2_kernel(
    const float* __restrict__ h2, const float* __restrict__ as,
    const float* __restrict__ ad, const int* __restrict__ off,
    const int* __restrict__ csr, const float* __restrict__ b2,
    float* __restrict__ out) {
  int gw = (blockIdx.x * blockDim.x + threadIdx.x) >> 6;
  int lane = threadIdx.x & 63;
  if (gw >= N_NODES) return;
  int base = off[gw];
  int deg  = off[gw + 1] - base;
  int g0 = lane / NCLS;           // 0..1
  int g1 = (lane + 64) / NCLS;    // 1..3
  int g2 = (lane + 128) / NCLS;   // 3 (lane<32)
  bool third = lane < 32;
  float ad0 = ad[gw*4 + g0], ad1 = ad[gw*4 + g1], ad2 = ad[gw*4 + g2];
  float m0 = -1e30f, m1 = -1e30f, m2 = -1e30f;
  float s0 = 0.f, s1 = 0.f, s2 = 0.f;
  float acc0 = 0.f, acc1 = 0.f, acc2 = 0.f;
  int j = 0;
  for (; j + 4 <= deg; j += 4) {
    int sr[4];
#pragma unroll
    for (int u = 0; u < 4; u++) sr[u] = csr[base + j + u];
    float e0[4], e1[4], e2[4], x0[4], x1[4], x2[4];
#pragma unroll
    for (int u = 0; u < 4; u++) {
      e0[u] = as[sr[u]*4 + g0]; e1[u] = as[sr[u]*4 + g1]; e2[u] = as[sr[u]*4 + g2];
    }
#pragma unroll
    for (int u = 0; u < 4; u++) {
      const float* r = h2 + (size_t)sr[u] * F2;
      x0[u] = r[lane]; x1[u] = r[64 + lane];
      x2[u] = third ? r[128 + lane] : 0.f;
    }
#pragma unroll
    for (int u = 0; u < 4; u++) {
      float v0 = e0[u] + ad0; v0 = v0 > 0.f ? v0 : NEG * v0;
      float v1 = e1[u] + ad1; v1 = v1 > 0.f ? v1 : NEG * v1;
      float v2 = e2[u] + ad2; v2 = v2 > 0.f ? v2 : NEG * v2;
      float n0 = fmaxf(m0, v0), n1 = fmaxf(m1, v1), n2 = fmaxf(m2, v2);
      float sc0 = __expf(m0 - n0), sc1 = __expf(m1 - n1), sc2 = __expf(m2 - n2);
      float w0 = __expf(v0 - n0), w1 = __expf(v1 - n1), w2 = __expf(v2 - n2);
      s0 = s0*sc0 + w0; s1 = s1*sc1 + w1; s2 = s2*sc2 + w2;
      acc0 = acc0*sc0 + w0*x0[u]; acc1 = acc1*sc1 + w1*x1[u]; acc2 = acc2*sc2 + w2*x2[u];
      m0 = n0; m1 = n1; m2 = n2;
    }
  }
  for (; j < deg; j++) {
    int src = csr[base + j];
    float v0 = as[src*4 + g0] + ad0; v0 = v0 > 0.f ? v0 : NEG * v0;
    float v1 = as[src*4 + g1] + ad1; v1 = v1 > 0.f ? v1 : NEG * v1;
    float v2 = as[src*4 + g2] + ad2; v2 = v2 > 0.f ? v2 : NEG * v2;
    const float* r = h2 + (size_t)src * F2;
    float x0 = r[lane], x1 = r[64 + lane];
    float x2 = third ? r[128 + lane] : 0.f;
    float n0 = fmaxf(m0, v0), n1 = fmaxf(m1, v1), n2 = fmaxf(m2, v2);
    float sc0 = __expf(m0 - n0), sc1 = __expf(m1 - n1), sc2 = __expf(m2 - n2);
    float w0 = __expf(v0 - n0), w1 = __expf(v1 - n1), w2 = __expf(v2 - n2);
    s0 = s0*sc0 + w0; s1 = s1*sc1 + w1; s2 = s2*sc2 + w2;
    acc0 = acc0*sc0 + w0*x0; acc1 = acc1*sc1 + w1*x1; acc2 = acc2*sc2 + w2*x2;
    m0 = n0; m1 = n1; m2 = n2;
  }
  out[(size_t)gw * F2 + lane]      = acc0/s0 + b2[lane];
  out[(size_t)gw * F2 + 64 + lane] = acc1/s1 + b2[64 + lane];
  if (third) out[(size_t)gw * F2 + 128 + lane] = acc2/s2 + b2[128 + lane];
}

extern "C" void kernel_launch(void* const* d_in, const int* in_sizes, int n_in,
                              void* d_out, int out_size, void* d_ws, size_t ws_size,
                              hipStream_t stream) {
  const float* x   = (const float*)d_in[0];
  const int*   ei  = (const int*)d_in[1];
  const float* bng = (const float*)d_in[2];
  const float* bnb = (const float*)d_in[3];
  const float* bnm = (const float*)d_in[4];
  const float* bnv = (const float*)d_in[5];
  const float* W1  = (const float*)d_in[6];
  const float* a1s = (const float*)d_in[7];
  const float* a1d = (const float*)d_in[8];
  const float* b1  = (const float*)d_in[9];
  const float* W2  = (const float*)d_in[10];
  const float* a2s = (const float*)d_in[11];
  const float* a2d = (const float*)d_in[12];
  const float* b2  = (const float*)d_in[13];
  float* out = (float*)d_out;

  char* ws = (char*)d_ws;
  size_t p = 0;
  auto alloc = [&](size_t bytes) -> char* {
    char* r = ws + p;
    p += (bytes + 255) & ~(size_t)255;
    return r;
  };
  float* h1   = (float*)alloc(sizeof(float) * (size_t)N_NODES * F1);   // 25.6MB
  float* h1a  = (float*)alloc(sizeof(float) * (size_t)N_NODES * F1);   // 25.6MB
  float* h2   = (float*)alloc(sizeof(float) * (size_t)N_NODES * F2);   // 32MB
  float* as1  = (float*)alloc(sizeof(float) * (size_t)N_NODES * HEADS);
  float* ad1  = (float*)alloc(sizeof(float) * (size_t)N_NODES * HEADS);
  float* as2  = (float*)alloc(sizeof(float) * (size_t)N_NODES * HEADS);
  float* ad2  = (float*)alloc(sizeof(float) * (size_t)N_NODES * HEADS);
  int* counts = (int*)alloc(sizeof(int) * (N_NODES + 1));
  int* offs   = (int*)alloc(sizeof(int) * (N_NODES + 1));
  int* fpos   = (int*)alloc(sizeof(int) * N_NODES);
  int* bsum   = (int*)alloc(sizeof(int) * SCAN_NB);
  int* bpre   = (int*)alloc(sizeof(int) * SCAN_NB);
  int* csr    = (int*)alloc(sizeof(int) * E_TOT);

  hipMemsetAsync(counts, 0, sizeof(int) * (N_NODES + 1), stream);

  // CSR build
  hist_kernel<<<(E_TOT + 255) / 256, 256, 0, stream>>>(ei, counts);
  partial_kernel<<<SCAN_NB, 256, 0, stream>>>(counts, bsum);
  bscan_kernel<<<1, 256, 0, stream>>>(bsum, bpre);
  scatter_kernel<<<SCAN_NB, 256, 0, stream>>>(counts, bpre, offs, fpos);
  fill_kernel<<<(E_TOT + 255) / 256, 256, 0, stream>>>(ei, fpos, csr);

  // layer 1
  int gblocks = (N_NODES + 31) / 32;   // 1563
  gemm1_kernel<<<gblocks, 256, 0, stream>>>(x, bng, bnb, bnm, bnv, W1, h1);
  alpha1_kernel<<<(N_NODES * HEADS + 255) / 256, 256, 0, stream>>>(h1, a1s, a1d, as1, ad1);
  agg1_kernel<<<(N_NODES + 3) / 4, 256, 0, stream>>>(h1, as1, ad1, offs, csr, b1, h1a);

  // layer 2
  gemm2_kernel<<<gblocks, 256, 0, stream>>>(h1a, W2, h2);
  alpha2_kernel<<<(N_NODES * HEADS + 255) / 256, 256, 0, stream>>>(h2, a2s, a2d, as2, ad2);
  agg2_kernel<<<(N_NODES + 3) / 4, 256, 0, stream>>>(h2, as2, ad2, offs, csr, b2, out);
}

// Round 5
// 458.883 us; speedup vs baseline: 1.5853x; 1.0213x over previous
//
#include <hip/hip_runtime.h>

#define N_NODES 50000
#define N_EDGES 800000
#define E_TOT   (N_EDGES + N_NODES)   // with self loops: 850000
#define IN_F    129
#define HID     32
#define HEADS   4
#define F1      (HEADS * HID)     // 128
#define NCLS    40
#define F2      (HEADS * NCLS)    // 160
#define NEG     0.2f
#define BN_EPS  1e-5f
#define PITCH1  132               // 129 padded to /4 alignment for float4 LDS reads
#define SCAN_NB ((N_NODES + 255) / 256)   // 196
#define LOG2E   1.4426950408889634f

// ---------------- GEMM1 (BN fused): [N,129] x [129,128] ----------------
__global__ __launch_bounds__(256) void gemm1_kernel(
    const float* __restrict__ x,
    const float* __restrict__ bng, const float* __restrict__ bnb,
    const float* __restrict__ bnm, const float* __restrict__ bnv,
    const float* __restrict__ W, float* __restrict__ h1) {
  __shared__ float scale[IN_F], shift[IN_F];
  __shared__ float rows[32 * PITCH1];
  int tid = threadIdx.x;
  if (tid < IN_F) {
    float sc = bng[tid] * rsqrtf(bnv[tid] + BN_EPS);
    scale[tid] = sc;
    shift[tid] = bnb[tid] - bnm[tid] * sc;
  }
  __syncthreads();
  int nb = blockIdx.x * 32;
  int nvalid = N_NODES - nb; if (nvalid > 32) nvalid = 32;
  const float* xb = x + (size_t)nb * IN_F;
  int total = nvalid * IN_F;
  for (int i = tid; i < total; i += 256) {
    int r = i / IN_F;
    int c = i - r * IN_F;
    rows[r * PITCH1 + c] = xb[i] * scale[c] + shift[c];
  }
  __syncthreads();
  int wave = tid >> 6, lane = tid & 63;
  int r0 = wave * 8;
  if (r0 >= nvalid) return;
  const float* rp[8];
#pragma unroll
  for (int i = 0; i < 8; i++) {
    int ri = r0 + i; if (ri >= nvalid) ri = nvalid - 1;
    rp[i] = &rows[ri * PITCH1];
  }
  float a0[8] = {}, a1[8] = {};
  for (int k = 0; k < 128; k += 4) {
    float4 xv[8];
#pragma unroll
    for (int i = 0; i < 8; i++) xv[i] = *(const float4*)(rp[i] + k);
    float w00 = W[(k+0)*F1 + lane],      w10 = W[(k+0)*F1 + 64 + lane];
    float w01 = W[(k+1)*F1 + lane],      w11 = W[(k+1)*F1 + 64 + lane];
    float w02 = W[(k+2)*F1 + lane],      w12 = W[(k+2)*F1 + 64 + lane];
    float w03 = W[(k+3)*F1 + lane],      w13 = W[(k+3)*F1 + 64 + lane];
#pragma unroll
    for (int i = 0; i < 8; i++) {
      a0[i] += xv[i].x*w00 + xv[i].y*w01 + xv[i].z*w02 + xv[i].w*w03;
      a1[i] += xv[i].x*w10 + xv[i].y*w11 + xv[i].z*w12 + xv[i].w*w13;
    }
  }
  { // k = 128 remainder
    float w0 = W[128*F1 + lane], w1 = W[128*F1 + 64 + lane];
#pragma unroll
    for (int i = 0; i < 8; i++) { float xk = rp[i][128]; a0[i] += xk*w0; a1[i] += xk*w1; }
  }
#pragma unroll
  for (int i = 0; i < 8; i++) {
    if (r0 + i >= nvalid) break;
    size_t n = nb + r0 + i;
    h1[n * F1 + lane]      = a0[i];
    h1[n * F1 + 64 + lane] = a1[i];
  }
}

// ---------------- GEMM2: [N,128] x [128,160] ----------------
__global__ __launch_bounds__(256) void gemm2_kernel(
    const float* __restrict__ hin, const float* __restrict__ W,
    float* __restrict__ hout) {
  __shared__ float rows[32 * F1];   // 16 KB
  int tid = threadIdx.x;
  int nb = blockIdx.x * 32;
  int nvalid = N_NODES - nb; if (nvalid > 32) nvalid = 32;
  const float4* src4 = (const float4*)(hin + (size_t)nb * F1);
  float4* dst4 = (float4*)rows;
  int tot4 = nvalid * (F1 / 4);
  for (int i = tid; i < tot4; i += 256) dst4[i] = src4[i];
  __syncthreads();
  int wave = tid >> 6, lane = tid & 63;
  int r0 = wave * 8;
  if (r0 >= nvalid) return;
  const float* rp[8];
#pragma unroll
  for (int i = 0; i < 8; i++) {
    int ri = r0 + i; if (ri >= nvalid) ri = nvalid - 1;
    rp[i] = &rows[ri * F1];
  }
  bool third = lane < 32;
  float a0[8] = {}, a1[8] = {}, a2[8] = {};
  for (int k = 0; k < F1; k += 4) {
    float4 xv[8];
#pragma unroll
    for (int i = 0; i < 8; i++) xv[i] = *(const float4*)(rp[i] + k);
    float w00 = W[(k+0)*F2 + lane], w10 = W[(k+0)*F2 + 64 + lane];
    float w01 = W[(k+1)*F2 + lane], w11 = W[(k+1)*F2 + 64 + lane];
    float w02 = W[(k+2)*F2 + lane], w12 = W[(k+2)*F2 + 64 + lane];
    float w03 = W[(k+3)*F2 + lane], w13 = W[(k+3)*F2 + 64 + lane];
    float w20 = third ? W[(k+0)*F2 + 128 + lane] : 0.f;
    float w21 = third ? W[(k+1)*F2 + 128 + lane] : 0.f;
    float w22 = third ? W[(k+2)*F2 + 128 + lane] : 0.f;
    float w23 = third ? W[(k+3)*F2 + 128 + lane] : 0.f;
#pragma unroll
    for (int i = 0; i < 8; i++) {
      a0[i] += xv[i].x*w00 + xv[i].y*w01 + xv[i].z*w02 + xv[i].w*w03;
      a1[i] += xv[i].x*w10 + xv[i].y*w11 + xv[i].z*w12 + xv[i].w*w13;
      a2[i] += xv[i].x*w20 + xv[i].y*w21 + xv[i].z*w22 + xv[i].w*w23;
    }
  }
#pragma unroll
  for (int i = 0; i < 8; i++) {
    if (r0 + i >= nvalid) break;
    size_t n = nb + r0 + i;
    hout[n * F2 + lane]      = a0[i];
    hout[n * F2 + 64 + lane] = a1[i];
    if (third) hout[n * F2 + 128 + lane] = a2[i];
  }
}

// ---------------- attention scalars (pre-scaled by log2(e)) ----------------
__global__ __launch_bounds__(256) void alpha1_kernel(
    const float* __restrict__ h1, const float* __restrict__ a_src,
    const float* __restrict__ a_dst, float* __restrict__ as,
    float* __restrict__ ad) {
  int t = blockIdx.x * 256 + threadIdx.x;
  if (t >= N_NODES * HEADS) return;
  int n = t >> 2, h = t & 3;
  const float* hp = h1 + (size_t)n * F1 + h * HID;
  const float* sp = a_src + h * HID;
  const float* dp = a_dst + h * HID;
  float s = 0.f, d = 0.f;
#pragma unroll
  for (int c = 0; c < HID; c++) { float v = hp[c]; s += v * sp[c]; d += v * dp[c]; }
  as[t] = s * LOG2E; ad[t] = d * LOG2E;
}

__global__ __launch_bounds__(256) void alpha2_kernel(
    const float* __restrict__ h2, const float* __restrict__ a_src,
    const float* __restrict__ a_dst, float* __restrict__ as,
    float* __restrict__ ad) {
  int t = blockIdx.x * 256 + threadIdx.x;
  if (t >= N_NODES * HEADS) return;
  int n = t >> 2, h = t & 3;
  const float* hp = h2 + (size_t)n * F2 + h * NCLS;
  const float* sp = a_src + h * NCLS;
  const float* dp = a_dst + h * NCLS;
  float s = 0.f, d = 0.f;
#pragma unroll
  for (int c = 0; c < NCLS; c++) { float v = hp[c]; s += v * sp[c]; d += v * dp[c]; }
  as[t] = s * LOG2E; ad[t] = d * LOG2E;
}

// ---------------- CSR build ----------------
__global__ __launch_bounds__(256) void hist_kernel(
    const int* __restrict__ ei, int* __restrict__ counts) {
  int e = blockIdx.x * 256 + threadIdx.x;
  if (e >= E_TOT) return;
  int dst = (e < N_EDGES) ? ei[N_EDGES + e] : (e - N_EDGES);
  atomicAdd(&counts[dst], 1);
}

__global__ __launch_bounds__(256) void partial_kernel(
    const int* __restrict__ counts, int* __restrict__ bsum) {
  __shared__ int red[4];
  int i = blockIdx.x * 256 + threadIdx.x;
  int v = (i < N_NODES) ? counts[i] : 0;
#pragma unroll
  for (int o = 1; o < 64; o <<= 1) v += __shfl_xor(v, o);
  int lane = threadIdx.x & 63, wave = threadIdx.x >> 6;
  if (lane == 0) red[wave] = v;
  __syncthreads();
  if (threadIdx.x == 0) bsum[blockIdx.x] = red[0] + red[1] + red[2] + red[3];
}

__global__ __launch_bounds__(256) void bscan_kernel(
    const int* __restrict__ bsum, int* __restrict__ bpre) {
  __shared__ int sh[256];
  int t = threadIdx.x;
  int v = (t < SCAN_NB) ? bsum[t] : 0;
  sh[t] = v;
  __syncthreads();
  for (int o = 1; o < 256; o <<= 1) {
    int u = (t >= o) ? sh[t - o] : 0;
    __syncthreads();
    sh[t] += u;
    __syncthreads();
  }
  if (t < SCAN_NB) bpre[t] = sh[t] - v;   // exclusive
}

__global__ __launch_bounds__(256) void scatter_kernel(
    const int* __restrict__ counts, const int* __restrict__ bpre,
    int* __restrict__ offsets, int* __restrict__ fillpos) {
  __shared__ int sh[256];
  int t = threadIdx.x;
  int i = blockIdx.x * 256 + t;
  int v = (i < N_NODES) ? counts[i] : 0;
  sh[t] = v;
  __syncthreads();
  for (int o = 1; o < 256; o <<= 1) {
    int u = (t >= o) ? sh[t - o] : 0;
    __syncthreads();
    sh[t] += u;
    __syncthreads();
  }
  if (i < N_NODES) {
    int excl = bpre[blockIdx.x] + sh[t] - v;
    offsets[i] = excl;
    fillpos[i] = excl;
  }
  if (i == 0) offsets[N_NODES] = E_TOT;
}

__global__ __launch_bounds__(256) void fill_kernel(
    const int* __restrict__ ei, int* __restrict__ fillpos,
    int* __restrict__ csr_src) {
  int e = blockIdx.x * 256 + threadIdx.x;
  if (e >= E_TOT) return;
  int src, dst;
  if (e < N_EDGES) { src = ei[e]; dst = ei[N_EDGES + e]; }
  else { src = dst = e - N_EDGES; }
  int pos = atomicAdd(&fillpos[dst], 1);
  csr_src[pos] = src;
}

// ---- aggregation layer 1: no-max softmax, 1 exp/edge + shfl broadcast -----
// one wave per node; lane covers f=lane, f=lane+64
__global__ __launch_bounds__(256) void agg1_kernel(
    const float* __restrict__ h1, const float* __restrict__ as,
    const float* __restrict__ ad, const int* __restrict__ off,
    const int* __restrict__ csr, const float* __restrict__ b1,
    float* __restrict__ out) {
  int gw = (blockIdx.x * blockDim.x + threadIdx.x) >> 6;
  int lane = threadIdx.x & 63;
  if (gw >= N_NODES) return;
  int base = off[gw];
  int deg  = off[gw + 1] - base;
  int h  = lane & 3;          // head this lane computes the weight for
  int g0 = lane >> 5;         // head of f=lane     (0..1)
  int g1 = 2 + (lane >> 5);   // head of f=lane+64  (2..3)
  float adh = ad[gw * 4 + h];
  float s = 0.f, acc0 = 0.f, acc1 = 0.f;
  int j = 0;
  for (; j + 4 <= deg; j += 4) {
    int sr[4];
#pragma unroll
    for (int u = 0; u < 4; u++) sr[u] = csr[base + j + u];
    float av[4], x0[4], x1[4];
#pragma unroll
    for (int u = 0; u < 4; u++) av[u] = as[sr[u]*4 + h];
#pragma unroll
    for (int u = 0; u < 4; u++) {
      const float* r = h1 + (size_t)sr[u] * F1;
      x0[u] = r[lane]; x1[u] = r[64 + lane];
    }
    float w[4];
#pragma unroll
    for (int u = 0; u < 4; u++) {
      float v = av[u] + adh;
      v = fmaxf(v, NEG * v);                 // leakyrelu (log2-domain)
      w[u] = __builtin_amdgcn_exp2f(v);
      s += w[u];
    }
#pragma unroll
    for (int u = 0; u < 4; u++) {
      float w0 = __shfl(w[u], g0);
      float w1 = __shfl(w[u], g1);
      acc0 += w0 * x0[u];
      acc1 += w1 * x1[u];
    }
  }
  for (; j < deg; j++) {
    int src = csr[base + j];
    float v = as[src*4 + h] + adh;
    v = fmaxf(v, NEG * v);
    float w = __builtin_amdgcn_exp2f(v);
    s += w;
    const float* r = h1 + (size_t)src * F1;
    float w0 = __shfl(w, g0);
    float w1 = __shfl(w, g1);
    acc0 += w0 * r[lane];
    acc1 += w1 * r[64 + lane];
  }
  float s0 = __shfl(s, g0), s1 = __shfl(s, g1);
  float o0 = acc0 / s0 + b1[lane];
  float o1 = acc1 / s1 + b1[64 + lane];
  o0 = o0 > 0.f ? o0 : expm1f(o0);   // ELU fused
  o1 = o1 > 0.f ? o1 : expm1f(o1);
  out[(size_t)gw * F1 + lane]      = o0;
  out[(size_t)gw * F1 + 64 + lane] = o1;
}

// ---- aggregation layer 2: no-max softmax, 1 exp/edge + shfl broadcast -----
// one wave per node; lane covers f=lane, lane+64, lane+128(lane<32)
__global__ __launch_bounds__(256) void agg2_kernel(
    const float* __restrict__ h2, const float* __restrict__ as,
    const float* __restrict__ ad, const int* __restrict__ off,
    const int* __restrict__ csr, const float* __restrict__ b2,
    float* __restrict__ out) {
  int gw = (blockIdx.x * blockDim.x + threadIdx.x) >> 6;
  int lane = threadIdx.x & 63;
  if (gw >= N_NODES) return;
  int base = off[gw];
  int deg  = off[gw + 1] - base;
  int h  = lane & 3;
  int g0 = lane / NCLS;           // 0..1
  int g1 = (lane + 64) / NCLS;    // 1..3
  const int g2 = 3;               // f=128..159 is all head 3
  bool third = lane < 32;
  float adh = ad[gw * 4 + h];
  float s = 0.f, acc0 = 0.f, acc1 = 0.f, acc2 = 0.f;
  int j = 0;
  for (; j + 4 <= deg; j += 4) {
    int sr[4];
#pragma unroll
    for (int u = 0; u < 4; u++) sr[u] = csr[base + j + u];
    float av[4], x0[4], x1[4], x2[4];
#pragma unroll
    for (int u = 0; u < 4; u++) av[u] = as[sr[u]*4 + h];
#pragma unroll
    for (int u = 0; u < 4; u++) {
      const float* r = h2 + (size_t)sr[u] * F2;
      x0[u] = r[lane]; x1[u] = r[64 + lane];
      x2[u] = third ? r[128 + lane] : 0.f;
    }
    float w[4];
#pragma unroll
    for (int u = 0; u < 4; u++) {
      float v = av[u] + adh;
      v = fmaxf(v, NEG * v);
      w[u] = __builtin_amdgcn_exp2f(v);
      s += w[u];
    }
#pragma unroll
    for (int u = 0; u < 4; u++) {
      float w0 = __shfl(w[u], g0);
      float w1 = __shfl(w[u], g1);
      float w2 = __shfl(w[u], g2);
      acc0 += w0 * x0[u];
      acc1 += w1 * x1[u];
      acc2 += w2 * x2[u];
    }
  }
  for (; j < deg; j++) {
    int src = csr[base + j];
    float v = as[src*4 + h] + adh;
    v = fmaxf(v, NEG * v);
    float w = __builtin_amdgcn_exp2f(v);
    s += w;
    const float* r = h2 + (size_t)src * F2;
    float x0 = r[lane], x1 = r[64 + lane];
    float x2 = third ? r[128 + lane] : 0.f;
    float w0 = __shfl(w, g0);
    float w1 = __shfl(w, g1);
    float w2 = __shfl(w, g2);
    acc0 += w0 * x0;
    acc1 += w1 * x1;
    acc2 += w2 * x2;
  }
  float s0 = __shfl(s, g0), s1 = __shfl(s, g1), s2 = __shfl(s, g2);
  out[(size_t)gw * F2 + lane]      = acc0/s0 + b2[lane];
  out[(size_t)gw * F2 + 64 + lane] = acc1/s1 + b2[64 + lane];
  if (third) out[(size_t)gw * F2 + 128 + lane] = acc2/s2 + b2[128 + lane];
}

extern "C" void kernel_launch(void* const* d_in, const int* in_sizes, int n_in,
                              void* d_out, int out_size, void* d_ws, size_t ws_size,
                              hipStream_t stream) {
  const float* x   = (const float*)d_in[0];
  const int*   ei  = (const int*)d_in[1];
  const float* bng = (const float*)d_in[2];
  const float* bnb = (const float*)d_in[3];
  const float* bnm = (const float*)d_in[4];
  const float* bnv = (const float*)d_in[5];
  const float* W1  = (const float*)d_in[6];
  const float* a1s = (const float*)d_in[7];
  const float* a1d = (const float*)d_in[8];
  const float* b1  = (const float*)d_in[9];
  const float* W2  = (const float*)d_in[10];
  const float* a2s = (const float*)d_in[11];
  const float* a2d = (const float*)d_in[12];
  const float* b2  = (const float*)d_in[13];
  float* out = (float*)d_out;

  char* ws = (char*)d_ws;
  size_t p = 0;
  auto alloc = [&](size_t bytes) -> char* {
    char* r = ws + p;
    p += (bytes + 255) & ~(size_t)255;
    return r;
  };
  float* h1   = (float*)alloc(sizeof(float) * (size_t)N_NODES * F1);   // 25.6MB
  float* h1a  = (float*)alloc(sizeof(float) * (size_t)N_NODES * F1);   // 25.6MB
  float* h2   = (float*)alloc(sizeof(float) * (size_t)N_NODES * F2);   // 32MB
  float* as1  = (float*)alloc(sizeof(float) * (size_t)N_NODES * HEADS);
  float* ad1  = (float*)alloc(sizeof(float) * (size_t)N_NODES * HEADS);
  float* as2  = (float*)alloc(sizeof(float) * (size_t)N_NODES * HEADS);
  float* ad2  = (float*)alloc(sizeof(float) * (size_t)N_NODES * HEADS);
  int* counts = (int*)alloc(sizeof(int) * (N_NODES + 1));
  int* offs   = (int*)alloc(sizeof(int) * (N_NODES + 1));
  int* fpos   = (int*)alloc(sizeof(int) * N_NODES);
  int* bsum   = (int*)alloc(sizeof(int) * SCAN_NB);
  int* bpre   = (int*)alloc(sizeof(int) * SCAN_NB);
  int* csr    = (int*)alloc(sizeof(int) * E_TOT);

  hipMemsetAsync(counts, 0, sizeof(int) * (N_NODES + 1), stream);

  // CSR build
  hist_kernel<<<(E_TOT + 255) / 256, 256, 0, stream>>>(ei, counts);
  partial_kernel<<<SCAN_NB, 256, 0, stream>>>(counts, bsum);
  bscan_kernel<<<1, 256, 0, stream>>>(bsum, bpre);
  scatter_kernel<<<SCAN_NB, 256, 0, stream>>>(counts, bpre, offs, fpos);
  fill_kernel<<<(E_TOT + 255) / 256, 256, 0, stream>>>(ei, fpos, csr);

  // layer 1
  int gblocks = (N_NODES + 31) / 32;   // 1563
  gemm1_kernel<<<gblocks, 256, 0, stream>>>(x, bng, bnb, bnm, bnv, W1, h1);
  alpha1_kernel<<<(N_NODES * HEADS + 255) / 256, 256, 0, stream>>>(h1, a1s, a1d, as1, ad1);
  agg1_kernel<<<(N_NODES + 3) / 4, 256, 0, stream>>>(h1, as1, ad1, offs, csr, b1, h1a);

  // layer 2
  gemm2_kernel<<<gblocks, 256, 0, stream>>>(h1a, W2, h2);
  alpha2_kernel<<<(N_NODES * HEADS + 255) / 256, 256, 0, stream>>>(h2, a2s, a2d, as2, ad2);
  agg2_kernel<<<(N_NODES + 3) / 4, 256, 0, stream>>>(h2, as2, ad2, offs, csr, b2, out);
}

// Round 6
// 444.731 us; speedup vs baseline: 1.6358x; 1.0318x over previous
//
#include <hip/hip_runtime.h>

#define N_NODES 50000
#define N_EDGES 800000
#define E_TOT   (N_EDGES + N_NODES)   // with self loops: 850000
#define IN_F    129
#define HID     32
#define HEADS   4
#define F1      (HEADS * HID)     // 128
#define NCLS    40
#define F2      (HEADS * NCLS)    // 160
#define NEG     0.2f
#define BN_EPS  1e-5f
#define PITCH1  132               // 129 padded to /4 alignment for float4 LDS reads
#define SCAN_NB ((N_NODES + 255) / 256)   // 196
#define LOG2E   1.4426950408889634f

__device__ __forceinline__ unsigned pack_bf16(float lo, float hi) {
  unsigned ul = __float_as_uint(lo), uh = __float_as_uint(hi);
  ul = (ul + 0x7FFFu + ((ul >> 16) & 1u)) >> 16;   // RNE
  uh = (uh + 0x7FFFu + ((uh >> 16) & 1u)) >> 16;
  return ul | (uh << 16);
}

// ---------------- GEMM1 (BN fused): [N,129] x [129,128] ----------------
// paired-column layout: lane computes channels 2l, 2l+1 (float2 W loads/stores)
__global__ __launch_bounds__(256) void gemm1_kernel(
    const float* __restrict__ x,
    const float* __restrict__ bng, const float* __restrict__ bnb,
    const float* __restrict__ bnm, const float* __restrict__ bnv,
    const float* __restrict__ W, float* __restrict__ h1) {
  __shared__ float scale[IN_F], shift[IN_F];
  __shared__ float rows[32 * PITCH1];
  int tid = threadIdx.x;
  if (tid < IN_F) {
    float sc = bng[tid] * rsqrtf(bnv[tid] + BN_EPS);
    scale[tid] = sc;
    shift[tid] = bnb[tid] - bnm[tid] * sc;
  }
  __syncthreads();
  int nb = blockIdx.x * 32;
  int nvalid = N_NODES - nb; if (nvalid > 32) nvalid = 32;
  const float* xb = x + (size_t)nb * IN_F;
  int total = nvalid * IN_F;
  for (int i = tid; i < total; i += 256) {
    int r = i / IN_F;
    int c = i - r * IN_F;
    rows[r * PITCH1 + c] = xb[i] * scale[c] + shift[c];
  }
  __syncthreads();
  int wave = tid >> 6, lane = tid & 63;
  int r0 = wave * 8;
  if (r0 >= nvalid) return;
  const float* rp[8];
#pragma unroll
  for (int i = 0; i < 8; i++) {
    int ri = r0 + i; if (ri >= nvalid) ri = nvalid - 1;
    rp[i] = &rows[ri * PITCH1];
  }
  float a0[8] = {}, a1[8] = {};
  for (int k = 0; k < 128; k += 4) {
    float4 xv[8];
#pragma unroll
    for (int i = 0; i < 8; i++) xv[i] = *(const float4*)(rp[i] + k);
    float2 w0 = *(const float2*)&W[(k+0)*F1 + 2*lane];
    float2 w1 = *(const float2*)&W[(k+1)*F1 + 2*lane];
    float2 w2 = *(const float2*)&W[(k+2)*F1 + 2*lane];
    float2 w3 = *(const float2*)&W[(k+3)*F1 + 2*lane];
#pragma unroll
    for (int i = 0; i < 8; i++) {
      a0[i] += xv[i].x*w0.x + xv[i].y*w1.x + xv[i].z*w2.x + xv[i].w*w3.x;
      a1[i] += xv[i].x*w0.y + xv[i].y*w1.y + xv[i].z*w2.y + xv[i].w*w3.y;
    }
  }
  { // k = 128 remainder
    float2 w = *(const float2*)&W[128*F1 + 2*lane];
#pragma unroll
    for (int i = 0; i < 8; i++) { float xk = rp[i][128]; a0[i] += xk*w.x; a1[i] += xk*w.y; }
  }
#pragma unroll
  for (int i = 0; i < 8; i++) {
    if (r0 + i >= nvalid) break;
    size_t n = nb + r0 + i;
    *(float2*)&h1[n * F1 + 2*lane] = make_float2(a0[i], a1[i]);
  }
}

// ---------------- GEMM2: [N,128] x [128,160] ----------------
// paired-column layout; writes f32 h2 (for alpha2) + packed bf16 h2b (for agg2)
__global__ __launch_bounds__(256) void gemm2_kernel(
    const float* __restrict__ hin, const float* __restrict__ W,
    float* __restrict__ hout, unsigned* __restrict__ h2b) {
  __shared__ float rows[32 * F1];   // 16 KB
  int tid = threadIdx.x;
  int nb = blockIdx.x * 32;
  int nvalid = N_NODES - nb; if (nvalid > 32) nvalid = 32;
  const float4* src4 = (const float4*)(hin + (size_t)nb * F1);
  float4* dst4 = (float4*)rows;
  int tot4 = nvalid * (F1 / 4);
  for (int i = tid; i < tot4; i += 256) dst4[i] = src4[i];
  __syncthreads();
  int wave = tid >> 6, lane = tid & 63;
  int r0 = wave * 8;
  if (r0 >= nvalid) return;
  const float* rp[8];
#pragma unroll
  for (int i = 0; i < 8; i++) {
    int ri = r0 + i; if (ri >= nvalid) ri = nvalid - 1;
    rp[i] = &rows[ri * F1];
  }
  bool third = lane < 16;
  float a0[8] = {}, a1[8] = {}, a2[8] = {}, a3[8] = {};
  for (int k = 0; k < F1; k += 4) {
    float4 xv[8];
#pragma unroll
    for (int i = 0; i < 8; i++) xv[i] = *(const float4*)(rp[i] + k);
    float2 w0 = *(const float2*)&W[(k+0)*F2 + 2*lane];
    float2 w1 = *(const float2*)&W[(k+1)*F2 + 2*lane];
    float2 w2 = *(const float2*)&W[(k+2)*F2 + 2*lane];
    float2 w3 = *(const float2*)&W[(k+3)*F2 + 2*lane];
    float2 q0 = third ? *(const float2*)&W[(k+0)*F2 + 128 + 2*lane] : make_float2(0.f,0.f);
    float2 q1 = third ? *(const float2*)&W[(k+1)*F2 + 128 + 2*lane] : make_float2(0.f,0.f);
    float2 q2 = third ? *(const float2*)&W[(k+2)*F2 + 128 + 2*lane] : make_float2(0.f,0.f);
    float2 q3 = third ? *(const float2*)&W[(k+3)*F2 + 128 + 2*lane] : make_float2(0.f,0.f);
#pragma unroll
    for (int i = 0; i < 8; i++) {
      a0[i] += xv[i].x*w0.x + xv[i].y*w1.x + xv[i].z*w2.x + xv[i].w*w3.x;
      a1[i] += xv[i].x*w0.y + xv[i].y*w1.y + xv[i].z*w2.y + xv[i].w*w3.y;
      a2[i] += xv[i].x*q0.x + xv[i].y*q1.x + xv[i].z*q2.x + xv[i].w*q3.x;
      a3[i] += xv[i].x*q0.y + xv[i].y*q1.y + xv[i].z*q2.y + xv[i].w*q3.y;
    }
  }
#pragma unroll
  for (int i = 0; i < 8; i++) {
    if (r0 + i >= nvalid) break;
    size_t n = nb + r0 + i;
    *(float2*)&hout[n * F2 + 2*lane] = make_float2(a0[i], a1[i]);
    h2b[n * (F2/2) + lane] = pack_bf16(a0[i], a1[i]);
    if (third) {
      *(float2*)&hout[n * F2 + 128 + 2*lane] = make_float2(a2[i], a3[i]);
      h2b[n * (F2/2) + 64 + lane] = pack_bf16(a2[i], a3[i]);
    }
  }
}

// ---------------- attention scalars (pre-scaled by log2(e)) ----------------
__global__ __launch_bounds__(256) void alpha1_kernel(
    const float* __restrict__ h1, const float* __restrict__ a_src,
    const float* __restrict__ a_dst, float* __restrict__ as,
    float* __restrict__ ad) {
  int t = blockIdx.x * 256 + threadIdx.x;
  if (t >= N_NODES * HEADS) return;
  int n = t >> 2, h = t & 3;
  const float* hp = h1 + (size_t)n * F1 + h * HID;
  const float* sp = a_src + h * HID;
  const float* dp = a_dst + h * HID;
  float s = 0.f, d = 0.f;
#pragma unroll
  for (int c = 0; c < HID; c++) { float v = hp[c]; s += v * sp[c]; d += v * dp[c]; }
  as[t] = s * LOG2E; ad[t] = d * LOG2E;
}

__global__ __launch_bounds__(256) void alpha2_kernel(
    const float* __restrict__ h2, const float* __restrict__ a_src,
    const float* __restrict__ a_dst, float* __restrict__ as,
    float* __restrict__ ad) {
  int t = blockIdx.x * 256 + threadIdx.x;
  if (t >= N_NODES * HEADS) return;
  int n = t >> 2, h = t & 3;
  const float* hp = h2 + (size_t)n * F2 + h * NCLS;
  const float* sp = a_src + h * NCLS;
  const float* dp = a_dst + h * NCLS;
  float s = 0.f, d = 0.f;
#pragma unroll
  for (int c = 0; c < NCLS; c++) { float v = hp[c]; s += v * sp[c]; d += v * dp[c]; }
  as[t] = s * LOG2E; ad[t] = d * LOG2E;
}

// ---------------- CSR build ----------------
__global__ __launch_bounds__(256) void hist_kernel(
    const int* __restrict__ ei, int* __restrict__ counts) {
  int e = blockIdx.x * 256 + threadIdx.x;
  if (e >= E_TOT) return;
  int dst = (e < N_EDGES) ? ei[N_EDGES + e] : (e - N_EDGES);
  atomicAdd(&counts[dst], 1);
}

__global__ __launch_bounds__(256) void partial_kernel(
    const int* __restrict__ counts, int* __restrict__ bsum) {
  __shared__ int red[4];
  int i = blockIdx.x * 256 + threadIdx.x;
  int v = (i < N_NODES) ? counts[i] : 0;
#pragma unroll
  for (int o = 1; o < 64; o <<= 1) v += __shfl_xor(v, o);
  int lane = threadIdx.x & 63, wave = threadIdx.x >> 6;
  if (lane == 0) red[wave] = v;
  __syncthreads();
  if (threadIdx.x == 0) bsum[blockIdx.x] = red[0] + red[1] + red[2] + red[3];
}

__global__ __launch_bounds__(256) void bscan_kernel(
    const int* __restrict__ bsum, int* __restrict__ bpre) {
  __shared__ int sh[256];
  int t = threadIdx.x;
  int v = (t < SCAN_NB) ? bsum[t] : 0;
  sh[t] = v;
  __syncthreads();
  for (int o = 1; o < 256; o <<= 1) {
    int u = (t >= o) ? sh[t - o] : 0;
    __syncthreads();
    sh[t] += u;
    __syncthreads();
  }
  if (t < SCAN_NB) bpre[t] = sh[t] - v;   // exclusive
}

__global__ __launch_bounds__(256) void scatter_kernel(
    const int* __restrict__ counts, const int* __restrict__ bpre,
    int* __restrict__ offsets, int* __restrict__ fillpos) {
  __shared__ int sh[256];
  int t = threadIdx.x;
  int i = blockIdx.x * 256 + t;
  int v = (i < N_NODES) ? counts[i] : 0;
  sh[t] = v;
  __syncthreads();
  for (int o = 1; o < 256; o <<= 1) {
    int u = (t >= o) ? sh[t - o] : 0;
    __syncthreads();
    sh[t] += u;
    __syncthreads();
  }
  if (i < N_NODES) {
    int excl = bpre[blockIdx.x] + sh[t] - v;
    offsets[i] = excl;
    fillpos[i] = excl;
  }
  if (i == 0) offsets[N_NODES] = E_TOT;
}

__global__ __launch_bounds__(256) void fill_kernel(
    const int* __restrict__ ei, int* __restrict__ fillpos,
    int* __restrict__ csr_src) {
  int e = blockIdx.x * 256 + threadIdx.x;
  if (e >= E_TOT) return;
  int src, dst;
  if (e < N_EDGES) { src = ei[e]; dst = ei[N_EDGES + e]; }
  else { src = dst = e - N_EDGES; }
  int pos = atomicAdd(&fillpos[dst], 1);
  csr_src[pos] = src;
}

// ---- aggregation layer 1: f32 float2 gather, 1 load + 1 shfl/edge, unroll 8
// lane covers channels 2l, 2l+1 (same head g = l>>4)
__global__ __launch_bounds__(256) void agg1_kernel(
    const float* __restrict__ h1, const float* __restrict__ as,
    const float* __restrict__ ad, const int* __restrict__ off,
    const int* __restrict__ csr, const float* __restrict__ b1,
    float* __restrict__ out) {
  int gw = (blockIdx.x * blockDim.x + threadIdx.x) >> 6;
  int lane = threadIdx.x & 63;
  if (gw >= N_NODES) return;
  int base = off[gw];
  int deg  = off[gw + 1] - base;
  int h = lane & 3;           // head this lane computes the weight for
  int g = lane >> 4;          // head of channels 2l, 2l+1
  float adh = ad[gw * 4 + h];
  float s = 0.f, acc0 = 0.f, acc1 = 0.f;
  int j = 0;
  for (; j + 8 <= deg; j += 8) {
    int sr[8];
#pragma unroll
    for (int u = 0; u < 8; u++) sr[u] = csr[base + j + u];
    float av[8];
#pragma unroll
    for (int u = 0; u < 8; u++) av[u] = as[sr[u]*4 + h];
    float2 xv[8];
#pragma unroll
    for (int u = 0; u < 8; u++)
      xv[u] = *(const float2*)(h1 + (size_t)sr[u] * F1 + 2*lane);
    float w[8];
#pragma unroll
    for (int u = 0; u < 8; u++) {
      float v = av[u] + adh;
      v = fmaxf(v, NEG * v);                 // leakyrelu (log2-domain)
      w[u] = __builtin_amdgcn_exp2f(v);
      s += w[u];
    }
#pragma unroll
    for (int u = 0; u < 8; u++) {
      float wg = __shfl(w[u], g);
      acc0 += wg * xv[u].x;
      acc1 += wg * xv[u].y;
    }
  }
  for (; j < deg; j++) {
    int src = csr[base + j];
    float v = as[src*4 + h] + adh;
    v = fmaxf(v, NEG * v);
    float w = __builtin_amdgcn_exp2f(v);
    s += w;
    float2 xv = *(const float2*)(h1 + (size_t)src * F1 + 2*lane);
    float wg = __shfl(w, g);
    acc0 += wg * xv.x;
    acc1 += wg * xv.y;
  }
  float sg = __shfl(s, g);
  float2 bp = *(const float2*)&b1[2*lane];
  float o0 = acc0 / sg + bp.x;
  float o1 = acc1 / sg + bp.y;
  o0 = o0 > 0.f ? o0 : expm1f(o0);   // ELU fused
  o1 = o1 > 0.f ? o1 : expm1f(o1);
  *(float2*)&out[(size_t)gw * F1 + 2*lane] = make_float2(o0, o1);
}

// ---- aggregation layer 2: bf16-packed gather, unroll 8 --------------------
// lane covers packed pair lane (ch 2l,2l+1) + pair 64+lane (lane<16, ch 128+2l)
__global__ __launch_bounds__(256) void agg2_kernel(
    const unsigned* __restrict__ h2b, const float* __restrict__ as,
    const float* __restrict__ ad, const int* __restrict__ off,
    const int* __restrict__ csr, const float* __restrict__ b2,
    float* __restrict__ out) {
  int gw = (blockIdx.x * blockDim.x + threadIdx.x) >> 6;
  int lane = threadIdx.x & 63;
  if (gw >= N_NODES) return;
  int base = off[gw];
  int deg  = off[gw + 1] - base;
  int h  = lane & 3;
  int gA = lane / 20;             // head of channels 2l,2l+1 (pairs never straddle)
  bool third = lane < 16;
  float adh = ad[gw * 4 + h];
  float s = 0.f, a0 = 0.f, a1 = 0.f, a2 = 0.f, a3 = 0.f;
  int j = 0;
  for (; j + 8 <= deg; j += 8) {
    int sr[8];
#pragma unroll
    for (int u = 0; u < 8; u++) sr[u] = csr[base + j + u];
    float av[8];
#pragma unroll
    for (int u = 0; u < 8; u++) av[u] = as[sr[u]*4 + h];
    unsigned ua[8], ub[8];
#pragma unroll
    for (int u = 0; u < 8; u++) {
      const unsigned* r = h2b + (size_t)sr[u] * (F2/2);
      ua[u] = r[lane];
      ub[u] = third ? r[64 + lane] : 0u;
    }
    float w[8];
#pragma unroll
    for (int u = 0; u < 8; u++) {
      float v = av[u] + adh;
      v = fmaxf(v, NEG * v);
      w[u] = __builtin_amdgcn_exp2f(v);
      s += w[u];
    }
#pragma unroll
    for (int u = 0; u < 8; u++) {
      float wA = __shfl(w[u], gA);
      float w3 = __shfl(w[u], 3);
      a0 += wA * __uint_as_float(ua[u] << 16);
      a1 += wA * __uint_as_float(ua[u] & 0xFFFF0000u);
      a2 += w3 * __uint_as_float(ub[u] << 16);
      a3 += w3 * __uint_as_float(ub[u] & 0xFFFF0000u);
    }
  }
  for (; j < deg; j++) {
    int src = csr[base + j];
    float v = as[src*4 + h] + adh;
    v = fmaxf(v, NEG * v);
    float w = __builtin_amdgcn_exp2f(v);
    s += w;
    const unsigned* r = h2b + (size_t)src * (F2/2);
    unsigned ua = r[lane];
    unsigned ub = third ? r[64 + lane] : 0u;
    float wA = __shfl(w, gA);
    float w3 = __shfl(w, 3);
    a0 += wA * __uint_as_float(ua << 16);
    a1 += wA * __uint_as_float(ua & 0xFFFF0000u);
    a2 += w3 * __uint_as_float(ub << 16);
    a3 += w3 * __uint_as_float(ub & 0xFFFF0000u);
  }
  float sA = __shfl(s, gA), s3 = __shfl(s, 3);
  float2 bp = *(const float2*)&b2[2*lane];
  *(float2*)&out[(size_t)gw * F2 + 2*lane] =
      make_float2(a0/sA + bp.x, a1/sA + bp.y);
  if (third) {
    float2 bq = *(const float2*)&b2[128 + 2*lane];
    *(float2*)&out[(size_t)gw * F2 + 128 + 2*lane] =
        make_float2(a2/s3 + bq.x, a3/s3 + bq.y);
  }
}

extern "C" void kernel_launch(void* const* d_in, const int* in_sizes, int n_in,
                              void* d_out, int out_size, void* d_ws, size_t ws_size,
                              hipStream_t stream) {
  const float* x   = (const float*)d_in[0];
  const int*   ei  = (const int*)d_in[1];
  const float* bng = (const float*)d_in[2];
  const float* bnb = (const float*)d_in[3];
  const float* bnm = (const float*)d_in[4];
  const float* bnv = (const float*)d_in[5];
  const float* W1  = (const float*)d_in[6];
  const float* a1s = (const float*)d_in[7];
  const float* a1d = (const float*)d_in[8];
  const float* b1  = (const float*)d_in[9];
  const float* W2  = (const float*)d_in[10];
  const float* a2s = (const float*)d_in[11];
  const float* a2d = (const float*)d_in[12];
  const float* b2  = (const float*)d_in[13];
  float* out = (float*)d_out;

  char* ws = (char*)d_ws;
  size_t p = 0;
  auto alloc = [&](size_t bytes) -> char* {
    char* r = ws + p;
    p += (bytes + 255) & ~(size_t)255;
    return r;
  };
  float* h1   = (float*)alloc(sizeof(float) * (size_t)N_NODES * F1);   // 25.6MB
  float* h1a  = (float*)alloc(sizeof(float) * (size_t)N_NODES * F1);   // 25.6MB
  float* h2   = (float*)alloc(sizeof(float) * (size_t)N_NODES * F2);   // 32MB
  float* as1  = (float*)alloc(sizeof(float) * (size_t)N_NODES * HEADS);
  float* ad1  = (float*)alloc(sizeof(float) * (size_t)N_NODES * HEADS);
  float* as2  = (float*)alloc(sizeof(float) * (size_t)N_NODES * HEADS);
  float* ad2  = (float*)alloc(sizeof(float) * (size_t)N_NODES * HEADS);
  int* counts = (int*)alloc(sizeof(int) * (N_NODES + 1));
  int* offs   = (int*)alloc(sizeof(int) * (N_NODES + 1));
  int* fpos   = (int*)alloc(sizeof(int) * N_NODES);
  int* bsum   = (int*)alloc(sizeof(int) * SCAN_NB);
  int* bpre   = (int*)alloc(sizeof(int) * SCAN_NB);
  int* csr    = (int*)alloc(sizeof(int) * E_TOT);
  // bf16 copy of h2 for agg2's gather; h1 is dead once gemm2 runs -> alias
  unsigned* h2b = (unsigned*)h1;   // N * 80 u32 = 16MB < 25.6MB

  hipMemsetAsync(counts, 0, sizeof(int) * (N_NODES + 1), stream);

  // CSR build
  hist_kernel<<<(E_TOT + 255) / 256, 256, 0, stream>>>(ei, counts);
  partial_kernel<<<SCAN_NB, 256, 0, stream>>>(counts, bsum);
  bscan_kernel<<<1, 256, 0, stream>>>(bsum, bpre);
  scatter_kernel<<<SCAN_NB, 256, 0, stream>>>(counts, bpre, offs, fpos);
  fill_kernel<<<(E_TOT + 255) / 256, 256, 0, stream>>>(ei, fpos, csr);

  // layer 1
  int gblocks = (N_NODES + 31) / 32;   // 1563
  gemm1_kernel<<<gblocks, 256, 0, stream>>>(x, bng, bnb, bnm, bnv, W1, h1);
  alpha1_kernel<<<(N_NODES * HEADS + 255) / 256, 256, 0, stream>>>(h1, a1s, a1d, as1, ad1);
  agg1_kernel<<<(N_NODES + 3) / 4, 256, 0, stream>>>(h1, as1, ad1, offs, csr, b1, h1a);

  // layer 2
  gemm2_kernel<<<gblocks, 256, 0, stream>>>(h1a, W2, h2, h2b);
  alpha2_kernel<<<(N_NODES * HEADS + 255) / 256, 256, 0, stream>>>(h2, a2s, a2d, as2, ad2);
  agg2_kernel<<<(N_NODES + 3) / 4, 256, 0, stream>>>(h2b, as2, ad2, offs, csr, b2, out);
}

// Round 7
// 382.645 us; speedup vs baseline: 1.9012x; 1.1623x over previous
//
#include <hip/hip_runtime.h>

#define N_NODES 50000
#define N_EDGES 800000
#define E_TOT   (N_EDGES + N_NODES)   // with self loops: 850000
#define IN_F    129
#define HID     32
#define HEADS   4
#define F1      (HEADS * HID)     // 128
#define NCLS    40
#define F2      (HEADS * NCLS)    // 160
#define NEG     0.2f
#define BN_EPS  1e-5f
#define SCAN_NB ((N_NODES + 255) / 256)   // 196
#define LOG2E   1.4426950408889634f

typedef __attribute__((ext_vector_type(8))) short bf16x8;
typedef __attribute__((ext_vector_type(4))) float f32x4;

#define P1_ELEMS (8 * 4 * 64 * 8)    // 16384: W1 fragments (8 ntiles x 4 kchunks)
#define P2_ELEMS (10 * 4 * 64 * 8)   // 20480: W2 fragments (10 ntiles x 4 kchunks)

__device__ __forceinline__ unsigned short bf16_rne(float f) {
  unsigned u = __float_as_uint(f);
  u = (u + 0x7FFFu + ((u >> 16) & 1u)) >> 16;
  return (unsigned short)u;
}
__device__ __forceinline__ float bf16_to_f(unsigned short s) {
  return __uint_as_float(((unsigned)s) << 16);
}
__device__ __forceinline__ unsigned pack_bf16(float lo, float hi) {
  return (unsigned)bf16_rne(lo) | ((unsigned)bf16_rne(hi) << 16);
}

// ---- pack W1/W2 into MFMA B-fragment layout, hi/lo bf16 split -------------
// B-frag (16x16x32): lane l supplies B[k=(l>>4)*8+i][col=l&15], i=0..7
// packed idx: ((t*4 + c)*64 + l)*8 + i
__global__ __launch_bounds__(256) void packw_kernel(
    const float* __restrict__ W1, const float* __restrict__ W2,
    unsigned short* __restrict__ p1h, unsigned short* __restrict__ p1l,
    unsigned short* __restrict__ p2h, unsigned short* __restrict__ p2l) {
  int e = blockIdx.x * 256 + threadIdx.x;
  if (e < P1_ELEMS) {
    int i = e & 7, l = (e >> 3) & 63, c = (e >> 9) & 3, t = e >> 11;
    int k = c * 32 + (l >> 4) * 8 + i;
    int col = t * 16 + (l & 15);
    float v = W1[k * F1 + col];
    unsigned short hi = bf16_rne(v);
    p1h[e] = hi;
    p1l[e] = bf16_rne(v - bf16_to_f(hi));
  }
  int e2 = e - P1_ELEMS;
  if (e2 >= 0 && e2 < P2_ELEMS) {
    int i = e2 & 7, l = (e2 >> 3) & 63, c = (e2 >> 9) & 3, t = e2 >> 11;
    int k = c * 32 + (l >> 4) * 8 + i;
    int col = t * 16 + (l & 15);
    float v = W2[k * F2 + col];
    unsigned short hi = bf16_rne(v);
    p2h[e2] = hi;
    p2l[e2] = bf16_rne(v - bf16_to_f(hi));
  }
}

// ---------------- GEMM1 (BN fused, MFMA 3xbf16): [N,129]x[129,128] ---------
// block = 256 (4 waves); wave computes 16 rows x 128 cols; k=128 tail on VALU
__global__ __launch_bounds__(256) void gemm1_kernel(
    const float* __restrict__ x,
    const float* __restrict__ bng, const float* __restrict__ bnb,
    const float* __restrict__ bnm, const float* __restrict__ bnv,
    const unsigned short* __restrict__ p1h, const unsigned short* __restrict__ p1l,
    const float* __restrict__ W1, float* __restrict__ h1) {
  __shared__ float scale[IN_F], shift[IN_F];
  int tid = threadIdx.x;
  if (tid < IN_F) {
    float sc = bng[tid] * rsqrtf(bnv[tid] + BN_EPS);
    scale[tid] = sc;
    shift[tid] = bnb[tid] - bnm[tid] * sc;
  }
  __syncthreads();
  int lane = tid & 63, wave = tid >> 6;
  int row0 = blockIdx.x * 64 + wave * 16;
  if (row0 >= N_NODES) return;
  int arow = row0 + (lane & 15);
  int arow_c = arow < N_NODES ? arow : N_NODES - 1;
  int kb = (lane >> 4) * 8;
  const float* xr = x + (size_t)arow_c * IN_F;
  bf16x8 ah[4], al[4];
#pragma unroll
  for (int c = 0; c < 4; c++) {
    int k0 = c * 32 + kb;
#pragma unroll
    for (int i = 0; i < 8; i++) {
      float a = xr[k0 + i] * scale[k0 + i] + shift[k0 + i];
      unsigned short hi = bf16_rne(a);
      ah[c][i] = (short)hi;
      al[c][i] = (short)bf16_rne(a - bf16_to_f(hi));
    }
  }
  // tail A (k=128) for this lane's 4 C-rows
  int crow_base = row0 + (lane >> 4) * 4;
  float atail[4];
#pragma unroll
  for (int r = 0; r < 4; r++) {
    int rr = crow_base + r;
    rr = rr < N_NODES ? rr : N_NODES - 1;
    atail[r] = x[(size_t)rr * IN_F + 128] * scale[128] + shift[128];
  }
  int col0 = lane & 15;
  for (int t = 0; t < 8; t++) {
    f32x4 acc = {0.f, 0.f, 0.f, 0.f};
#pragma unroll
    for (int c = 0; c < 4; c++) {
      bf16x8 bh = *(const bf16x8*)(p1h + ((t * 4 + c) * 64 + lane) * 8);
      bf16x8 bl = *(const bf16x8*)(p1l + ((t * 4 + c) * 64 + lane) * 8);
      acc = __builtin_amdgcn_mfma_f32_16x16x32_bf16(ah[c], bh, acc, 0, 0, 0);
      acc = __builtin_amdgcn_mfma_f32_16x16x32_bf16(al[c], bh, acc, 0, 0, 0);
      acc = __builtin_amdgcn_mfma_f32_16x16x32_bf16(ah[c], bl, acc, 0, 0, 0);
    }
    int col = t * 16 + col0;
    float wtail = W1[128 * F1 + col];
#pragma unroll
    for (int r = 0; r < 4; r++) {
      int rr = crow_base + r;
      if (rr < N_NODES)
        h1[(size_t)rr * F1 + col] = acc[r] + atail[r] * wtail;
    }
  }
}

// ---------------- GEMM2 (MFMA 3xbf16): [N,128]x[128,160] -------------------
// writes f32 h2 (alpha2) + packed-bf16 h2b (agg2) via lane-pair shfl
__global__ __launch_bounds__(256) void gemm2_kernel(
    const float* __restrict__ hin,
    const unsigned short* __restrict__ p2h, const unsigned short* __restrict__ p2l,
    float* __restrict__ h2, unsigned* __restrict__ h2b) {
  int tid = threadIdx.x;
  int lane = tid & 63, wave = tid >> 6;
  int row0 = blockIdx.x * 64 + wave * 16;
  if (row0 >= N_NODES) return;
  int arow = row0 + (lane & 15);
  int arow_c = arow < N_NODES ? arow : N_NODES - 1;
  int kb = (lane >> 4) * 8;
  const float* hr = hin + (size_t)arow_c * F1;
  bf16x8 ah[4], al[4];
#pragma unroll
  for (int c = 0; c < 4; c++) {
    float4 v0 = *(const float4*)(hr + c * 32 + kb);
    float4 v1 = *(const float4*)(hr + c * 32 + kb + 4);
    float av[8] = {v0.x, v0.y, v0.z, v0.w, v1.x, v1.y, v1.z, v1.w};
#pragma unroll
    for (int i = 0; i < 8; i++) {
      unsigned short hi = bf16_rne(av[i]);
      ah[c][i] = (short)hi;
      al[c][i] = (short)bf16_rne(av[i] - bf16_to_f(hi));
    }
  }
  int crow_base = row0 + (lane >> 4) * 4;
  int col0 = lane & 15;
  for (int t = 0; t < 10; t++) {
    f32x4 acc = {0.f, 0.f, 0.f, 0.f};
#pragma unroll
    for (int c = 0; c < 4; c++) {
      bf16x8 bh = *(const bf16x8*)(p2h + ((t * 4 + c) * 64 + lane) * 8);
      bf16x8 bl = *(const bf16x8*)(p2l + ((t * 4 + c) * 64 + lane) * 8);
      acc = __builtin_amdgcn_mfma_f32_16x16x32_bf16(ah[c], bh, acc, 0, 0, 0);
      acc = __builtin_amdgcn_mfma_f32_16x16x32_bf16(al[c], bh, acc, 0, 0, 0);
      acc = __builtin_amdgcn_mfma_f32_16x16x32_bf16(ah[c], bl, acc, 0, 0, 0);
    }
    int col = t * 16 + col0;
#pragma unroll
    for (int r = 0; r < 4; r++) {
      int rr = crow_base + r;
      float odd = __shfl(acc[r], lane + 1);   // partner col (same row group)
      if (rr < N_NODES) {
        h2[(size_t)rr * F2 + col] = acc[r];
        if ((lane & 1) == 0)
          h2b[(size_t)rr * (F2 / 2) + (col >> 1)] = pack_bf16(acc[r], odd);
      }
    }
  }
}

// ---------------- attention scalars (pre-scaled by log2(e)) ----------------
__global__ __launch_bounds__(256) void alpha1_kernel(
    const float* __restrict__ h1, const float* __restrict__ a_src,
    const float* __restrict__ a_dst, float* __restrict__ as,
    float* __restrict__ ad) {
  int t = blockIdx.x * 256 + threadIdx.x;
  if (t >= N_NODES * HEADS) return;
  int n = t >> 2, h = t & 3;
  const float* hp = h1 + (size_t)n * F1 + h * HID;
  const float* sp = a_src + h * HID;
  const float* dp = a_dst + h * HID;
  float s = 0.f, d = 0.f;
#pragma unroll
  for (int c = 0; c < HID; c++) { float v = hp[c]; s += v * sp[c]; d += v * dp[c]; }
  as[t] = s * LOG2E; ad[t] = d * LOG2E;
}

__global__ __launch_bounds__(256) void alpha2_kernel(
    const float* __restrict__ h2, const float* __restrict__ a_src,
    const float* __restrict__ a_dst, float* __restrict__ as,
    float* __restrict__ ad) {
  int t = blockIdx.x * 256 + threadIdx.x;
  if (t >= N_NODES * HEADS) return;
  int n = t >> 2, h = t & 3;
  const float* hp = h2 + (size_t)n * F2 + h * NCLS;
  const float* sp = a_src + h * NCLS;
  const float* dp = a_dst + h * NCLS;
  float s = 0.f, d = 0.f;
#pragma unroll
  for (int c = 0; c < NCLS; c++) { float v = hp[c]; s += v * sp[c]; d += v * dp[c]; }
  as[t] = s * LOG2E; ad[t] = d * LOG2E;
}

// ---------------- CSR build ----------------
__global__ __launch_bounds__(256) void hist_kernel(
    const int* __restrict__ ei, int* __restrict__ counts) {
  int e = blockIdx.x * 256 + threadIdx.x;
  if (e >= E_TOT) return;
  int dst = (e < N_EDGES) ? ei[N_EDGES + e] : (e - N_EDGES);
  atomicAdd(&counts[dst], 1);
}

__global__ __launch_bounds__(256) void partial_kernel(
    const int* __restrict__ counts, int* __restrict__ bsum) {
  __shared__ int red[4];
  int i = blockIdx.x * 256 + threadIdx.x;
  int v = (i < N_NODES) ? counts[i] : 0;
#pragma unroll
  for (int o = 1; o < 64; o <<= 1) v += __shfl_xor(v, o);
  int lane = threadIdx.x & 63, wave = threadIdx.x >> 6;
  if (lane == 0) red[wave] = v;
  __syncthreads();
  if (threadIdx.x == 0) bsum[blockIdx.x] = red[0] + red[1] + red[2] + red[3];
}

__global__ __launch_bounds__(256) void bscan_kernel(
    const int* __restrict__ bsum, int* __restrict__ bpre) {
  __shared__ int sh[256];
  int t = threadIdx.x;
  int v = (t < SCAN_NB) ? bsum[t] : 0;
  sh[t] = v;
  __syncthreads();
  for (int o = 1; o < 256; o <<= 1) {
    int u = (t >= o) ? sh[t - o] : 0;
    __syncthreads();
    sh[t] += u;
    __syncthreads();
  }
  if (t < SCAN_NB) bpre[t] = sh[t] - v;   // exclusive
}

__global__ __launch_bounds__(256) void scatter_kernel(
    const int* __restrict__ counts, const int* __restrict__ bpre,
    int* __restrict__ offsets, int* __restrict__ fillpos) {
  __shared__ int sh[256];
  int t = threadIdx.x;
  int i = blockIdx.x * 256 + t;
  int v = (i < N_NODES) ? counts[i] : 0;
  sh[t] = v;
  __syncthreads();
  for (int o = 1; o < 256; o <<= 1) {
    int u = (t >= o) ? sh[t - o] : 0;
    __syncthreads();
    sh[t] += u;
    __syncthreads();
  }
  if (i < N_NODES) {
    int excl = bpre[blockIdx.x] + sh[t] - v;
    offsets[i] = excl;
    fillpos[i] = excl;
  }
  if (i == 0) offsets[N_NODES] = E_TOT;
}

__global__ __launch_bounds__(256) void fill_kernel(
    const int* __restrict__ ei, int* __restrict__ fillpos,
    int* __restrict__ csr_src) {
  int e = blockIdx.x * 256 + threadIdx.x;
  if (e >= E_TOT) return;
  int src, dst;
  if (e < N_EDGES) { src = ei[e]; dst = ei[N_EDGES + e]; }
  else { src = dst = e - N_EDGES; }
  int pos = atomicAdd(&fillpos[dst], 1);
  csr_src[pos] = src;
}

// ---- aggregation layer 1: f32 float2 gather, 1 load + 1 shfl/edge, unroll 8
__global__ __launch_bounds__(256) void agg1_kernel(
    const float* __restrict__ h1, const float* __restrict__ as,
    const float* __restrict__ ad, const int* __restrict__ off,
    const int* __restrict__ csr, const float* __restrict__ b1,
    float* __restrict__ out) {
  int gw = (blockIdx.x * blockDim.x + threadIdx.x) >> 6;
  int lane = threadIdx.x & 63;
  if (gw >= N_NODES) return;
  int base = off[gw];
  int deg  = off[gw + 1] - base;
  int h = lane & 3;
  int g = lane >> 4;          // head of channels 2l, 2l+1
  float adh = ad[gw * 4 + h];
  float s = 0.f, acc0 = 0.f, acc1 = 0.f;
  int j = 0;
  for (; j + 8 <= deg; j += 8) {
    int sr[8];
#pragma unroll
    for (int u = 0; u < 8; u++) sr[u] = csr[base + j + u];
    float av[8];
#pragma unroll
    for (int u = 0; u < 8; u++) av[u] = as[sr[u]*4 + h];
    float2 xv[8];
#pragma unroll
    for (int u = 0; u < 8; u++)
      xv[u] = *(const float2*)(h1 + (size_t)sr[u] * F1 + 2*lane);
    float w[8];
#pragma unroll
    for (int u = 0; u < 8; u++) {
      float v = av[u] + adh;
      v = fmaxf(v, NEG * v);
      w[u] = __builtin_amdgcn_exp2f(v);
      s += w[u];
    }
#pragma unroll
    for (int u = 0; u < 8; u++) {
      float wg = __shfl(w[u], g);
      acc0 += wg * xv[u].x;
      acc1 += wg * xv[u].y;
    }
  }
  for (; j < deg; j++) {
    int src = csr[base + j];
    float v = as[src*4 + h] + adh;
    v = fmaxf(v, NEG * v);
    float w = __builtin_amdgcn_exp2f(v);
    s += w;
    float2 xv = *(const float2*)(h1 + (size_t)src * F1 + 2*lane);
    float wg = __shfl(w, g);
    acc0 += wg * xv.x;
    acc1 += wg * xv.y;
  }
  float sg = __shfl(s, g);
  float2 bp = *(const float2*)&b1[2*lane];
  float o0 = acc0 / sg + bp.x;
  float o1 = acc1 / sg + bp.y;
  o0 = o0 > 0.f ? o0 : expm1f(o0);   // ELU fused
  o1 = o1 > 0.f ? o1 : expm1f(o1);
  *(float2*)&out[(size_t)gw * F1 + 2*lane] = make_float2(o0, o1);
}

// ---- aggregation layer 2: bf16-packed gather, unroll 8 --------------------
__global__ __launch_bounds__(256) void agg2_kernel(
    const unsigned* __restrict__ h2b, const float* __restrict__ as,
    const float* __restrict__ ad, const int* __restrict__ off,
    const int* __restrict__ csr, const float* __restrict__ b2,
    float* __restrict__ out) {
  int gw = (blockIdx.x * blockDim.x + threadIdx.x) >> 6;
  int lane = threadIdx.x & 63;
  if (gw >= N_NODES) return;
  int base = off[gw];
  int deg  = off[gw + 1] - base;
  int h  = lane & 3;
  int gA = lane / 20;
  bool third = lane < 16;
  float adh = ad[gw * 4 + h];
  float s = 0.f, a0 = 0.f, a1 = 0.f, a2 = 0.f, a3 = 0.f;
  int j = 0;
  for (; j + 8 <= deg; j += 8) {
    int sr[8];
#pragma unroll
    for (int u = 0; u < 8; u++) sr[u] = csr[base + j + u];
    float av[8];
#pragma unroll
    for (int u = 0; u < 8; u++) av[u] = as[sr[u]*4 + h];
    unsigned ua[8], ub[8];
#pragma unroll
    for (int u = 0; u < 8; u++) {
      const unsigned* r = h2b + (size_t)sr[u] * (F2/2);
      ua[u] = r[lane];
      ub[u] = third ? r[64 + lane] : 0u;
    }
    float w[8];
#pragma unroll
    for (int u = 0; u < 8; u++) {
      float v = av[u] + adh;
      v = fmaxf(v, NEG * v);
      w[u] = __builtin_amdgcn_exp2f(v);
      s += w[u];
    }
#pragma unroll
    for (int u = 0; u < 8; u++) {
      float wA = __shfl(w[u], gA);
      float w3 = __shfl(w[u], 3);
      a0 += wA * __uint_as_float(ua[u] << 16);
      a1 += wA * __uint_as_float(ua[u] & 0xFFFF0000u);
      a2 += w3 * __uint_as_float(ub[u] << 16);
      a3 += w3 * __uint_as_float(ub[u] & 0xFFFF0000u);
    }
  }
  for (; j < deg; j++) {
    int src = csr[base + j];
    float v = as[src*4 + h] + adh;
    v = fmaxf(v, NEG * v);
    float w = __builtin_amdgcn_exp2f(v);
    s += w;
    const unsigned* r = h2b + (size_t)src * (F2/2);
    unsigned ua = r[lane];
    unsigned ub = third ? r[64 + lane] : 0u;
    float wA = __shfl(w, gA);
    float w3 = __shfl(w, 3);
    a0 += wA * __uint_as_float(ua << 16);
    a1 += wA * __uint_as_float(ua & 0xFFFF0000u);
    a2 += w3 * __uint_as_float(ub << 16);
    a3 += w3 * __uint_as_float(ub & 0xFFFF0000u);
  }
  float sA = __shfl(s, gA), s3 = __shfl(s, 3);
  float2 bp = *(const float2*)&b2[2*lane];
  *(float2*)&out[(size_t)gw * F2 + 2*lane] =
      make_float2(a0/sA + bp.x, a1/sA + bp.y);
  if (third) {
    float2 bq = *(const float2*)&b2[128 + 2*lane];
    *(float2*)&out[(size_t)gw * F2 + 128 + 2*lane] =
        make_float2(a2/s3 + bq.x, a3/s3 + bq.y);
  }
}

extern "C" void kernel_launch(void* const* d_in, const int* in_sizes, int n_in,
                              void* d_out, int out_size, void* d_ws, size_t ws_size,
                              hipStream_t stream) {
  const float* x   = (const float*)d_in[0];
  const int*   ei  = (const int*)d_in[1];
  const float* bng = (const float*)d_in[2];
  const float* bnb = (const float*)d_in[3];
  const float* bnm = (const float*)d_in[4];
  const float* bnv = (const float*)d_in[5];
  const float* W1  = (const float*)d_in[6];
  const float* a1s = (const float*)d_in[7];
  const float* a1d = (const float*)d_in[8];
  const float* b1  = (const float*)d_in[9];
  const float* W2  = (const float*)d_in[10];
  const float* a2s = (const float*)d_in[11];
  const float* a2d = (const float*)d_in[12];
  const float* b2  = (const float*)d_in[13];
  float* out = (float*)d_out;

  char* ws = (char*)d_ws;
  size_t p = 0;
  auto alloc = [&](size_t bytes) -> char* {
    char* r = ws + p;
    p += (bytes + 255) & ~(size_t)255;
    return r;
  };
  float* h1   = (float*)alloc(sizeof(float) * (size_t)N_NODES * F1);   // 25.6MB
  float* h1a  = (float*)alloc(sizeof(float) * (size_t)N_NODES * F1);   // 25.6MB
  float* h2   = (float*)alloc(sizeof(float) * (size_t)N_NODES * F2);   // 32MB
  float* as1  = (float*)alloc(sizeof(float) * (size_t)N_NODES * HEADS);
  float* ad1  = (float*)alloc(sizeof(float) * (size_t)N_NODES * HEADS);
  float* as2  = (float*)alloc(sizeof(float) * (size_t)N_NODES * HEADS);
  float* ad2  = (float*)alloc(sizeof(float) * (size_t)N_NODES * HEADS);
  int* counts = (int*)alloc(sizeof(int) * (N_NODES + 1));
  int* offs   = (int*)alloc(sizeof(int) * (N_NODES + 1));
  int* fpos   = (int*)alloc(sizeof(int) * N_NODES);
  int* bsum   = (int*)alloc(sizeof(int) * SCAN_NB);
  int* bpre   = (int*)alloc(sizeof(int) * SCAN_NB);
  int* csr    = (int*)alloc(sizeof(int) * E_TOT);
  unsigned short* p1h = (unsigned short*)alloc(sizeof(unsigned short) * P1_ELEMS);
  unsigned short* p1l = (unsigned short*)alloc(sizeof(unsigned short) * P1_ELEMS);
  unsigned short* p2h = (unsigned short*)alloc(sizeof(unsigned short) * P2_ELEMS);
  unsigned short* p2l = (unsigned short*)alloc(sizeof(unsigned short) * P2_ELEMS);
  // bf16 copy of h2 for agg2's gather; h1 dead once gemm2 runs -> alias
  unsigned* h2b = (unsigned*)h1;   // N * 80 u32 = 16MB < 25.6MB

  hipMemsetAsync(counts, 0, sizeof(int) * (N_NODES + 1), stream);

  // weight packing (independent of everything else)
  packw_kernel<<<(P1_ELEMS + P2_ELEMS + 255) / 256, 256, 0, stream>>>(
      W1, W2, p1h, p1l, p2h, p2l);

  // CSR build
  hist_kernel<<<(E_TOT + 255) / 256, 256, 0, stream>>>(ei, counts);
  partial_kernel<<<SCAN_NB, 256, 0, stream>>>(counts, bsum);
  bscan_kernel<<<1, 256, 0, stream>>>(bsum, bpre);
  scatter_kernel<<<SCAN_NB, 256, 0, stream>>>(counts, bpre, offs, fpos);
  fill_kernel<<<(E_TOT + 255) / 256, 256, 0, stream>>>(ei, fpos, csr);

  // layer 1
  int gblocks = (N_NODES + 63) / 64;   // 782
  gemm1_kernel<<<gblocks, 256, 0, stream>>>(x, bng, bnb, bnm, bnv, p1h, p1l, W1, h1);
  alpha1_kernel<<<(N_NODES * HEADS + 255) / 256, 256, 0, stream>>>(h1, a1s, a1d, as1, ad1);
  agg1_kernel<<<(N_NODES + 3) / 4, 256, 0, stream>>>(h1, as1, ad1, offs, csr, b1, h1a);

  // layer 2
  gemm2_kernel<<<gblocks, 256, 0, stream>>>(h1a, p2h, p2l, h2, h2b);
  alpha2_kernel<<<(N_NODES * HEADS + 255) / 256, 256, 0, stream>>>(h2, a2s, a2d, as2, ad2);
  agg2_kernel<<<(N_NODES + 3) / 4, 256, 0, stream>>>(h2b, as2, ad2, offs, csr, b2, out);
}

// Round 8
// 368.653 us; speedup vs baseline: 1.9734x; 1.0380x over previous
//
#include <hip/hip_runtime.h>
#include <hip/hip_fp16.h>

#define N_NODES 50000
#define N_EDGES 800000
#define E_TOT   (N_EDGES + N_NODES)   // with self loops: 850000
#define IN_F    129
#define HID     32
#define HEADS   4
#define F1      (HEADS * HID)     // 128
#define NCLS    40
#define F2      (HEADS * NCLS)    // 160
#define NEG     0.2f
#define BN_EPS  1e-5f
#define SCAN_NB ((N_NODES + 255) / 256)   // 196
#define LOG2E   1.4426950408889634f

typedef __attribute__((ext_vector_type(8))) short bf16x8;
typedef __attribute__((ext_vector_type(4))) float f32x4;

#define P1_ELEMS (8 * 4 * 64 * 8)    // 16384: W1 fragments (8 ntiles x 4 kchunks)
#define P2_ELEMS (10 * 4 * 64 * 8)   // 20480: W2 fragments (10 ntiles x 4 kchunks)

__device__ __forceinline__ unsigned short bf16_rne(float f) {
  unsigned u = __float_as_uint(f);
  u = (u + 0x7FFFu + ((u >> 16) & 1u)) >> 16;
  return (unsigned short)u;
}
__device__ __forceinline__ float bf16_to_f(unsigned short s) {
  return __uint_as_float(((unsigned)s) << 16);
}
__device__ __forceinline__ unsigned pack_f16(float a, float b) {
  __half2 h = __floats2half2_rn(a, b);
  return *reinterpret_cast<unsigned*>(&h);
}
__device__ __forceinline__ float2 unpack_f16(unsigned u) {
  __half2 h = *reinterpret_cast<__half2*>(&u);
  return __half22float2(h);
}

// ---- pack W1/W2 into MFMA B-fragment layout, hi/lo bf16 split -------------
// B-frag (16x16x32): lane l supplies B[k=(l>>4)*8+i][col=l&15], i=0..7
__global__ __launch_bounds__(256) void packw_kernel(
    const float* __restrict__ W1, const float* __restrict__ W2,
    unsigned short* __restrict__ p1h, unsigned short* __restrict__ p1l,
    unsigned short* __restrict__ p2h, unsigned short* __restrict__ p2l) {
  int e = blockIdx.x * 256 + threadIdx.x;
  if (e < P1_ELEMS) {
    int i = e & 7, l = (e >> 3) & 63, c = (e >> 9) & 3, t = e >> 11;
    int k = c * 32 + (l >> 4) * 8 + i;
    int col = t * 16 + (l & 15);
    float v = W1[k * F1 + col];
    unsigned short hi = bf16_rne(v);
    p1h[e] = hi;
    p1l[e] = bf16_rne(v - bf16_to_f(hi));
  }
  int e2 = e - P1_ELEMS;
  if (e2 >= 0 && e2 < P2_ELEMS) {
    int i = e2 & 7, l = (e2 >> 3) & 63, c = (e2 >> 9) & 3, t = e2 >> 11;
    int k = c * 32 + (l >> 4) * 8 + i;
    int col = t * 16 + (l & 15);
    float v = W2[k * F2 + col];
    unsigned short hi = bf16_rne(v);
    p2h[e2] = hi;
    p2l[e2] = bf16_rne(v - bf16_to_f(hi));
  }
}

// ---------------- GEMM1 (BN fused, MFMA 3xbf16): [N,129]x[129,128] ---------
// wave computes 16 rows x 128 cols; k=128 tail on VALU; emits f32 h1 + fp16 h1b
__global__ __launch_bounds__(256) void gemm1_kernel(
    const float* __restrict__ x,
    const float* __restrict__ bng, const float* __restrict__ bnb,
    const float* __restrict__ bnm, const float* __restrict__ bnv,
    const unsigned short* __restrict__ p1h, const unsigned short* __restrict__ p1l,
    const float* __restrict__ W1, float* __restrict__ h1,
    unsigned* __restrict__ h1b) {
  __shared__ float scale[IN_F], shift[IN_F];
  int tid = threadIdx.x;
  if (tid < IN_F) {
    float sc = bng[tid] * rsqrtf(bnv[tid] + BN_EPS);
    scale[tid] = sc;
    shift[tid] = bnb[tid] - bnm[tid] * sc;
  }
  __syncthreads();
  int lane = tid & 63, wave = tid >> 6;
  int row0 = blockIdx.x * 64 + wave * 16;
  if (row0 >= N_NODES) return;
  int arow = row0 + (lane & 15);
  int arow_c = arow < N_NODES ? arow : N_NODES - 1;
  int kb = (lane >> 4) * 8;
  const float* xr = x + (size_t)arow_c * IN_F;
  bf16x8 ah[4], al[4];
#pragma unroll
  for (int c = 0; c < 4; c++) {
    int k0 = c * 32 + kb;
#pragma unroll
    for (int i = 0; i < 8; i++) {
      float a = xr[k0 + i] * scale[k0 + i] + shift[k0 + i];
      unsigned short hi = bf16_rne(a);
      ah[c][i] = (short)hi;
      al[c][i] = (short)bf16_rne(a - bf16_to_f(hi));
    }
  }
  int crow_base = row0 + (lane >> 4) * 4;
  float atail[4];
#pragma unroll
  for (int r = 0; r < 4; r++) {
    int rr = crow_base + r;
    rr = rr < N_NODES ? rr : N_NODES - 1;
    atail[r] = x[(size_t)rr * IN_F + 128] * scale[128] + shift[128];
  }
  int col0 = lane & 15;
  for (int t = 0; t < 8; t++) {
    f32x4 acc = {0.f, 0.f, 0.f, 0.f};
#pragma unroll
    for (int c = 0; c < 4; c++) {
      bf16x8 bh = *(const bf16x8*)(p1h + ((t * 4 + c) * 64 + lane) * 8);
      bf16x8 bl = *(const bf16x8*)(p1l + ((t * 4 + c) * 64 + lane) * 8);
      acc = __builtin_amdgcn_mfma_f32_16x16x32_bf16(ah[c], bh, acc, 0, 0, 0);
      acc = __builtin_amdgcn_mfma_f32_16x16x32_bf16(al[c], bh, acc, 0, 0, 0);
      acc = __builtin_amdgcn_mfma_f32_16x16x32_bf16(ah[c], bl, acc, 0, 0, 0);
    }
    int col = t * 16 + col0;
    float wtail = W1[128 * F1 + col];
#pragma unroll
    for (int r = 0; r < 4; r++) {
      float fin = acc[r] + atail[r] * wtail;
      float odd = __shfl(fin, lane + 1);    // partner column value
      int rr = crow_base + r;
      if (rr < N_NODES) {
        h1[(size_t)rr * F1 + col] = fin;
        if ((col0 & 1) == 0)
          h1b[(size_t)rr * (F1 / 2) + (col >> 1)] = pack_f16(fin, odd);
      }
    }
  }
}

// ---------------- GEMM2 (MFMA 3xbf16): [N,128]x[128,160] -------------------
// writes f32 h2 (alpha2) + packed-fp16 h2b (agg2) via lane-pair shfl
__global__ __launch_bounds__(256) void gemm2_kernel(
    const float* __restrict__ hin,
    const unsigned short* __restrict__ p2h, const unsigned short* __restrict__ p2l,
    float* __restrict__ h2, unsigned* __restrict__ h2b) {
  int tid = threadIdx.x;
  int lane = tid & 63, wave = tid >> 6;
  int row0 = blockIdx.x * 64 + wave * 16;
  if (row0 >= N_NODES) return;
  int arow = row0 + (lane & 15);
  int arow_c = arow < N_NODES ? arow : N_NODES - 1;
  int kb = (lane >> 4) * 8;
  const float* hr = hin + (size_t)arow_c * F1;
  bf16x8 ah[4], al[4];
#pragma unroll
  for (int c = 0; c < 4; c++) {
    float4 v0 = *(const float4*)(hr + c * 32 + kb);
    float4 v1 = *(const float4*)(hr + c * 32 + kb + 4);
    float av[8] = {v0.x, v0.y, v0.z, v0.w, v1.x, v1.y, v1.z, v1.w};
#pragma unroll
    for (int i = 0; i < 8; i++) {
      unsigned short hi = bf16_rne(av[i]);
      ah[c][i] = (short)hi;
      al[c][i] = (short)bf16_rne(av[i] - bf16_to_f(hi));
    }
  }
  int crow_base = row0 + (lane >> 4) * 4;
  int col0 = lane & 15;
  for (int t = 0; t < 10; t++) {
    f32x4 acc = {0.f, 0.f, 0.f, 0.f};
#pragma unroll
    for (int c = 0; c < 4; c++) {
      bf16x8 bh = *(const bf16x8*)(p2h + ((t * 4 + c) * 64 + lane) * 8);
      bf16x8 bl = *(const bf16x8*)(p2l + ((t * 4 + c) * 64 + lane) * 8);
      acc = __builtin_amdgcn_mfma_f32_16x16x32_bf16(ah[c], bh, acc, 0, 0, 0);
      acc = __builtin_amdgcn_mfma_f32_16x16x32_bf16(al[c], bh, acc, 0, 0, 0);
      acc = __builtin_amdgcn_mfma_f32_16x16x32_bf16(ah[c], bl, acc, 0, 0, 0);
    }
    int col = t * 16 + col0;
#pragma unroll
    for (int r = 0; r < 4; r++) {
      int rr = crow_base + r;
      float odd = __shfl(acc[r], lane + 1);
      if (rr < N_NODES) {
        h2[(size_t)rr * F2 + col] = acc[r];
        if ((lane & 1) == 0)
          h2b[(size_t)rr * (F2 / 2) + (col >> 1)] = pack_f16(acc[r], odd);
      }
    }
  }
}

// ---------------- attention scalars (pre-scaled by log2(e)) ----------------
__global__ __launch_bounds__(256) void alpha1_kernel(
    const float* __restrict__ h1, const float* __restrict__ a_src,
    const float* __restrict__ a_dst, float* __restrict__ as,
    float* __restrict__ ad) {
  int t = blockIdx.x * 256 + threadIdx.x;
  if (t >= N_NODES * HEADS) return;
  int n = t >> 2, h = t & 3;
  const float* hp = h1 + (size_t)n * F1 + h * HID;
  const float* sp = a_src + h * HID;
  const float* dp = a_dst + h * HID;
  float s = 0.f, d = 0.f;
#pragma unroll
  for (int c = 0; c < HID; c++) { float v = hp[c]; s += v * sp[c]; d += v * dp[c]; }
  as[t] = s * LOG2E; ad[t] = d * LOG2E;
}

__global__ __launch_bounds__(256) void alpha2_kernel(
    const float* __restrict__ h2, const float* __restrict__ a_src,
    const float* __restrict__ a_dst, float* __restrict__ as,
    float* __restrict__ ad) {
  int t = blockIdx.x * 256 + threadIdx.x;
  if (t >= N_NODES * HEADS) return;
  int n = t >> 2, h = t & 3;
  const float* hp = h2 + (size_t)n * F2 + h * NCLS;
  const float* sp = a_src + h * NCLS;
  const float* dp = a_dst + h * NCLS;
  float s = 0.f, d = 0.f;
#pragma unroll
  for (int c = 0; c < NCLS; c++) { float v = hp[c]; s += v * sp[c]; d += v * dp[c]; }
  as[t] = s * LOG2E; ad[t] = d * LOG2E;
}

// ---------------- CSR build ----------------
__global__ __launch_bounds__(256) void hist_kernel(
    const int* __restrict__ ei, int* __restrict__ counts) {
  int e = blockIdx.x * 256 + threadIdx.x;
  if (e >= E_TOT) return;
  int dst = (e < N_EDGES) ? ei[N_EDGES + e] : (e - N_EDGES);
  atomicAdd(&counts[dst], 1);
}

__global__ __launch_bounds__(256) void partial_kernel(
    const int* __restrict__ counts, int* __restrict__ bsum) {
  __shared__ int red[4];
  int i = blockIdx.x * 256 + threadIdx.x;
  int v = (i < N_NODES) ? counts[i] : 0;
#pragma unroll
  for (int o = 1; o < 64; o <<= 1) v += __shfl_xor(v, o);
  int lane = threadIdx.x & 63, wave = threadIdx.x >> 6;
  if (lane == 0) red[wave] = v;
  __syncthreads();
  if (threadIdx.x == 0) bsum[blockIdx.x] = red[0] + red[1] + red[2] + red[3];
}

__global__ __launch_bounds__(256) void bscan_kernel(
    const int* __restrict__ bsum, int* __restrict__ bpre) {
  __shared__ int sh[256];
  int t = threadIdx.x;
  int v = (t < SCAN_NB) ? bsum[t] : 0;
  sh[t] = v;
  __syncthreads();
  for (int o = 1; o < 256; o <<= 1) {
    int u = (t >= o) ? sh[t - o] : 0;
    __syncthreads();
    sh[t] += u;
    __syncthreads();
  }
  if (t < SCAN_NB) bpre[t] = sh[t] - v;   // exclusive
}

__global__ __launch_bounds__(256) void scatter_kernel(
    const int* __restrict__ counts, const int* __restrict__ bpre,
    int* __restrict__ offsets, int* __restrict__ fillpos) {
  __shared__ int sh[256];
  int t = threadIdx.x;
  int i = blockIdx.x * 256 + t;
  int v = (i < N_NODES) ? counts[i] : 0;
  sh[t] = v;
  __syncthreads();
  for (int o = 1; o < 256; o <<= 1) {
    int u = (t >= o) ? sh[t - o] : 0;
    __syncthreads();
    sh[t] += u;
    __syncthreads();
  }
  if (i < N_NODES) {
    int excl = bpre[blockIdx.x] + sh[t] - v;
    offsets[i] = excl;
    fillpos[i] = excl;
  }
  if (i == 0) offsets[N_NODES] = E_TOT;
}

__global__ __launch_bounds__(256) void fill_kernel(
    const int* __restrict__ ei, int* __restrict__ fillpos,
    int* __restrict__ csr_src) {
  int e = blockIdx.x * 256 + threadIdx.x;
  if (e >= E_TOT) return;
  int src, dst;
  if (e < N_EDGES) { src = ei[e]; dst = ei[N_EDGES + e]; }
  else { src = dst = e - N_EDGES; }
  int pos = atomicAdd(&fillpos[dst], 1);
  csr_src[pos] = src;
}

// ---- aggregation layer 1: fp16-packed gather, unroll 8 --------------------
// lane covers channels 2l, 2l+1 (same head g = l>>4)
__global__ __launch_bounds__(256) void agg1_kernel(
    const unsigned* __restrict__ h1b, const float* __restrict__ as,
    const float* __restrict__ ad, const int* __restrict__ off,
    const int* __restrict__ csr, const float* __restrict__ b1,
    float* __restrict__ out) {
  int gw = (blockIdx.x * blockDim.x + threadIdx.x) >> 6;
  int lane = threadIdx.x & 63;
  if (gw >= N_NODES) return;
  int base = off[gw];
  int deg  = off[gw + 1] - base;
  int h = lane & 3;
  int g = lane >> 4;          // head of channels 2l, 2l+1
  float adh = ad[gw * 4 + h];
  float s = 0.f, acc0 = 0.f, acc1 = 0.f;
  int j = 0;
  for (; j + 8 <= deg; j += 8) {
    int sr[8];
#pragma unroll
    for (int u = 0; u < 8; u++) sr[u] = csr[base + j + u];
    float av[8];
#pragma unroll
    for (int u = 0; u < 8; u++) av[u] = as[sr[u]*4 + h];
    unsigned uv[8];
#pragma unroll
    for (int u = 0; u < 8; u++)
      uv[u] = h1b[(size_t)sr[u] * (F1/2) + lane];
    float w[8];
#pragma unroll
    for (int u = 0; u < 8; u++) {
      float v = av[u] + adh;
      v = fmaxf(v, NEG * v);                 // leakyrelu (log2-domain)
      w[u] = __builtin_amdgcn_exp2f(v);
      s += w[u];
    }
#pragma unroll
    for (int u = 0; u < 8; u++) {
      float wg = __shfl(w[u], g);
      float2 xv = unpack_f16(uv[u]);
      acc0 += wg * xv.x;
      acc1 += wg * xv.y;
    }
  }
  for (; j < deg; j++) {
    int src = csr[base + j];
    float v = as[src*4 + h] + adh;
    v = fmaxf(v, NEG * v);
    float w = __builtin_amdgcn_exp2f(v);
    s += w;
    unsigned uv = h1b[(size_t)src * (F1/2) + lane];
    float wg = __shfl(w, g);
    float2 xv = unpack_f16(uv);
    acc0 += wg * xv.x;
    acc1 += wg * xv.y;
  }
  float sg = __shfl(s, g);
  float2 bp = *(const float2*)&b1[2*lane];
  float o0 = acc0 / sg + bp.x;
  float o1 = acc1 / sg + bp.y;
  o0 = o0 > 0.f ? o0 : expm1f(o0);   // ELU fused
  o1 = o1 > 0.f ? o1 : expm1f(o1);
  *(float2*)&out[(size_t)gw * F1 + 2*lane] = make_float2(o0, o1);
}

// ---- aggregation layer 2: fp16-packed gather, unroll 8 --------------------
__global__ __launch_bounds__(256) void agg2_kernel(
    const unsigned* __restrict__ h2b, const float* __restrict__ as,
    const float* __restrict__ ad, const int* __restrict__ off,
    const int* __restrict__ csr, const float* __restrict__ b2,
    float* __restrict__ out) {
  int gw = (blockIdx.x * blockDim.x + threadIdx.x) >> 6;
  int lane = threadIdx.x & 63;
  if (gw >= N_NODES) return;
  int base = off[gw];
  int deg  = off[gw + 1] - base;
  int h  = lane & 3;
  int gA = lane / 20;
  bool third = lane < 16;
  float adh = ad[gw * 4 + h];
  float s = 0.f, a0 = 0.f, a1 = 0.f, a2 = 0.f, a3 = 0.f;
  int j = 0;
  for (; j + 8 <= deg; j += 8) {
    int sr[8];
#pragma unroll
    for (int u = 0; u < 8; u++) sr[u] = csr[base + j + u];
    float av[8];
#pragma unroll
    for (int u = 0; u < 8; u++) av[u] = as[sr[u]*4 + h];
    unsigned ua[8], ub[8];
#pragma unroll
    for (int u = 0; u < 8; u++) {
      const unsigned* r = h2b + (size_t)sr[u] * (F2/2);
      ua[u] = r[lane];
      ub[u] = third ? r[64 + lane] : 0u;
    }
    float w[8];
#pragma unroll
    for (int u = 0; u < 8; u++) {
      float v = av[u] + adh;
      v = fmaxf(v, NEG * v);
      w[u] = __builtin_amdgcn_exp2f(v);
      s += w[u];
    }
#pragma unroll
    for (int u = 0; u < 8; u++) {
      float wA = __shfl(w[u], gA);
      float w3 = __shfl(w[u], 3);
      float2 fa = unpack_f16(ua[u]);
      float2 fb = unpack_f16(ub[u]);
      a0 += wA * fa.x;
      a1 += wA * fa.y;
      a2 += w3 * fb.x;
      a3 += w3 * fb.y;
    }
  }
  for (; j < deg; j++) {
    int src = csr[base + j];
    float v = as[src*4 + h] + adh;
    v = fmaxf(v, NEG * v);
    float w = __builtin_amdgcn_exp2f(v);
    s += w;
    const unsigned* r = h2b + (size_t)src * (F2/2);
    unsigned ua = r[lane];
    unsigned ub = third ? r[64 + lane] : 0u;
    float wA = __shfl(w, gA);
    float w3 = __shfl(w, 3);
    float2 fa = unpack_f16(ua);
    float2 fb = unpack_f16(ub);
    a0 += wA * fa.x;
    a1 += wA * fa.y;
    a2 += w3 * fb.x;
    a3 += w3 * fb.y;
  }
  float sA = __shfl(s, gA), s3 = __shfl(s, 3);
  float2 bp = *(const float2*)&b2[2*lane];
  *(float2*)&out[(size_t)gw * F2 + 2*lane] =
      make_float2(a0/sA + bp.x, a1/sA + bp.y);
  if (third) {
    float2 bq = *(const float2*)&b2[128 + 2*lane];
    *(float2*)&out[(size_t)gw * F2 + 128 + 2*lane] =
        make_float2(a2/s3 + bq.x, a3/s3 + bq.y);
  }
}

extern "C" void kernel_launch(void* const* d_in, const int* in_sizes, int n_in,
                              void* d_out, int out_size, void* d_ws, size_t ws_size,
                              hipStream_t stream) {
  const float* x   = (const float*)d_in[0];
  const int*   ei  = (const int*)d_in[1];
  const float* bng = (const float*)d_in[2];
  const float* bnb = (const float*)d_in[3];
  const float* bnm = (const float*)d_in[4];
  const float* bnv = (const float*)d_in[5];
  const float* W1  = (const float*)d_in[6];
  const float* a1s = (const float*)d_in[7];
  const float* a1d = (const float*)d_in[8];
  const float* b1  = (const float*)d_in[9];
  const float* W2  = (const float*)d_in[10];
  const float* a2s = (const float*)d_in[11];
  const float* a2d = (const float*)d_in[12];
  const float* b2  = (const float*)d_in[13];
  float* out = (float*)d_out;

  char* ws = (char*)d_ws;
  size_t p = 0;
  auto alloc = [&](size_t bytes) -> char* {
    char* r = ws + p;
    p += (bytes + 255) & ~(size_t)255;
    return r;
  };
  float* h1   = (float*)alloc(sizeof(float) * (size_t)N_NODES * F1);   // 25.6MB
  float* h1a  = (float*)alloc(sizeof(float) * (size_t)N_NODES * F1);   // 25.6MB
  float* h2   = (float*)alloc(sizeof(float) * (size_t)N_NODES * F2);   // 32MB
  unsigned* h1b = (unsigned*)alloc(sizeof(unsigned) * (size_t)N_NODES * (F1/2)); // 12.8MB
  float* as1  = (float*)alloc(sizeof(float) * (size_t)N_NODES * HEADS);
  float* ad1  = (float*)alloc(sizeof(float) * (size_t)N_NODES * HEADS);
  float* as2  = (float*)alloc(sizeof(float) * (size_t)N_NODES * HEADS);
  float* ad2  = (float*)alloc(sizeof(float) * (size_t)N_NODES * HEADS);
  int* counts = (int*)alloc(sizeof(int) * (N_NODES + 1));
  int* offs   = (int*)alloc(sizeof(int) * (N_NODES + 1));
  int* fpos   = (int*)alloc(sizeof(int) * N_NODES);
  int* bsum   = (int*)alloc(sizeof(int) * SCAN_NB);
  int* bpre   = (int*)alloc(sizeof(int) * SCAN_NB);
  int* csr    = (int*)alloc(sizeof(int) * E_TOT);
  unsigned short* p1h = (unsigned short*)alloc(sizeof(unsigned short) * P1_ELEMS);
  unsigned short* p1l = (unsigned short*)alloc(sizeof(unsigned short) * P1_ELEMS);
  unsigned short* p2h = (unsigned short*)alloc(sizeof(unsigned short) * P2_ELEMS);
  unsigned short* p2l = (unsigned short*)alloc(sizeof(unsigned short) * P2_ELEMS);
  // fp16 copy of h2 for agg2's gather; h1 dead once gemm2 runs -> alias
  unsigned* h2b = (unsigned*)h1;   // N * 80 u32 = 16MB < 25.6MB

  hipMemsetAsync(counts, 0, sizeof(int) * (N_NODES + 1), stream);

  // weight packing (independent of everything else)
  packw_kernel<<<(P1_ELEMS + P2_ELEMS + 255) / 256, 256, 0, stream>>>(
      W1, W2, p1h, p1l, p2h, p2l);

  // CSR build
  hist_kernel<<<(E_TOT + 255) / 256, 256, 0, stream>>>(ei, counts);
  partial_kernel<<<SCAN_NB, 256, 0, stream>>>(counts, bsum);
  bscan_kernel<<<1, 256, 0, stream>>>(bsum, bpre);
  scatter_kernel<<<SCAN_NB, 256, 0, stream>>>(counts, bpre, offs, fpos);
  fill_kernel<<<(E_TOT + 255) / 256, 256, 0, stream>>>(ei, fpos, csr);

  // layer 1
  int gblocks = (N_NODES + 63) / 64;   // 782
  gemm1_kernel<<<gblocks, 256, 0, stream>>>(x, bng, bnb, bnm, bnv, p1h, p1l, W1, h1, h1b);
  alpha1_kernel<<<(N_NODES * HEADS + 255) / 256, 256, 0, stream>>>(h1, a1s, a1d, as1, ad1);
  agg1_kernel<<<(N_NODES + 3) / 4, 256, 0, stream>>>(h1b, as1, ad1, offs, csr, b1, h1a);

  // layer 2
  gemm2_kernel<<<gblocks, 256, 0, stream>>>(h1a, p2h, p2l, h2, h2b);
  alpha2_kernel<<<(N_NODES * HEADS + 255) / 256, 256, 0, stream>>>(h2, a2s, a2d, as2, ad2);
  agg2_kernel<<<(N_NODES + 3) / 4, 256, 0, stream>>>(h2b, as2, ad2, offs, csr, b2, out);
}